// Round 7
// baseline (594.502 us; speedup 1.0000x reference)
//
#include <hip/hip_runtime.h>
#include <hip/hip_bf16.h>

typedef __hip_bfloat16 bf16;
typedef unsigned short u16;

#define NN 50000      // nodes
#define NE 1600000    // edges (= 6250*256 exactly)
#define NG 128        // graphs
#define NB 128        // rna batch
#define SG 3000       // global seq (channels)
#define SL 2998       // local seq
#define VG 5          // global vocab
#define VL 65         // local vocab
#define EDB 6250      // edge blocks (NE/256)
#define AGB 12500     // agg blocks (NN/4)
#define NA  (NB*VG + NB*VL)   // 1490 buildA blocks
#define NGB (32*VG + 32*VL)   // 2240 buildG blocks
#define CASTB ((NN*40+255)/256)  // 7813

__device__ __forceinline__ float b2f(bf16 x){ return __bfloat162float(x); }
__device__ __forceinline__ float blo(unsigned u){ return __uint_as_float(u << 16); }
__device__ __forceinline__ float bhi(unsigned u){ return __uint_as_float(u & 0xffff0000u); }

// ---------------- k_front: bucketing U edge_deg U transposeW U bias0 -------
__global__ void k_front(const int* __restrict__ rna_g, const int* __restrict__ rna_l,
                        int* __restrict__ tcnt_g, int* __restrict__ toff_g,
                        u16* __restrict__ bucket_g,
                        int* __restrict__ tcnt_l, int* __restrict__ toff_l,
                        u16* __restrict__ bucket_l,
                        const float* __restrict__ convW1, const float* __restrict__ convW2,
                        float* __restrict__ Wr1, float* __restrict__ Wr2,
                        const float* __restrict__ fcxrW, const float* __restrict__ cb1,
                        const float* __restrict__ cb2, float* __restrict__ bias0,
                        const int* __restrict__ dst, const float* __restrict__ ew,
                        double* __restrict__ packed, int* __restrict__ slot){
    int bx = blockIdx.x;
    int t = threadIdx.x;
    if (bx < 2*NB){
        __shared__ int hist[VL], pre[VL], cur[VL];
        int br = bx & 1, b = bx >> 1;
        const int* tok = br ? rna_l : rna_g;
        int S = br ? SL : SG, V = br ? VL : VG;
        int* tcnt = br ? tcnt_l : tcnt_g;
        int* toff = br ? toff_l : toff_g;
        u16* bucket = br ? bucket_l : bucket_g;
        if (t < V) hist[t] = 0;
        __syncthreads();
        for (int i = t; i < S; i += 256) atomicAdd(&hist[tok[b*S + i]], 1);
        __syncthreads();
        if (t == 0){
            int run = 0;
            for (int v = 0; v < V; ++v){ pre[v] = run; run += hist[v]; }
        }
        __syncthreads();
        if (t < V){
            tcnt[b*V + t] = hist[t];
            toff[b*V + t] = pre[t];
            cur[t] = pre[t];
        }
        __syncthreads();
        for (int i = t; i < S; i += 256){
            int v = tok[b*S + i];
            int p = atomicAdd(&cur[v], 1);
            bucket[b*S + p] = (u16)i;
        }
        return;
    }
    bx -= 2*NB;
    if (bx < EDB){
        int e = bx*256 + t;
        double old = unsafeAtomicAdd(&packed[dst[e]], 1048576.0 + (double)ew[e]);
        slot[e] = (int)(old * (1.0/1048576.0));
        return;
    }
    bx -= EDB;
    if (bx < SG + SL){
        const float* W; float* Wr; int S, c = bx;
        if (c < SG){ W = convW1; Wr = Wr1; S = SG; }
        else { c -= SG; W = convW2; Wr = Wr2; S = SL; }
        Wr[c*256 + t] = W[((t >> 3)*S + c)*8 + (t & 7)];
        return;
    }
    bx -= SG + SL;
    if (t >= 128) return;
    int o = bx, j = t;
    float s = 0.f;
    const float* Wo = fcxrW + o*121*128 + j;
    for (int l = 0; l < 121; ++l) s += Wo[l*128];
    unsafeAtomicAdd(&bias0[j], 0.5f * (cb1[o] + cb2[o]) * s);
}

// ---------------- buildA: K index k' = v*256 + t  (coalesced store) --------
// NOTE invariant: gemmR pairs X[b, k'] with G[k', j]. Both A and G use
// k' = v*256 + (o*8+k); gemmR's 256-wide kpart chunks == v partitions.
__device__ void dev_buildA(const float* __restrict__ Wr, const u16* __restrict__ bucket,
                           const int* __restrict__ toff, const int* __restrict__ tcnt,
                           float* __restrict__ A, int S, int V, int bv){
    int b = bv / V, v = bv - b*V;
    int t = threadIdx.x;            // t = o*8+k
    const u16* bk = bucket + b*S + toff[b*V + v];
    int m = tcnt[b*V + v];
    float acc = 0.f;
    int idx = 0;
    for (; idx + 4 <= m; idx += 4){
        int c0 = bk[idx], c1 = bk[idx+1], c2 = bk[idx+2], c3 = bk[idx+3];
        acc += Wr[c0*256 + t];
        acc += Wr[c1*256 + t];
        acc += Wr[c2*256 + t];
        acc += Wr[c3*256 + t];
    }
    for (; idx < m; ++idx) acc += Wr[bk[idx]*256 + t];
    A[b*(256*V) + v*256 + t] = acc;   // contiguous in t: 1KB coalesced/block
}

// ---------------- F1: buildA (fp32 Wr) + prep + out0 init ------------------
__global__ void k_F1(const float* __restrict__ Wr1, const float* __restrict__ Wr2,
                     const u16* __restrict__ bucket_g, const int* __restrict__ toff_g,
                     const int* __restrict__ tcnt_g, float* __restrict__ Ag,
                     const u16* __restrict__ bucket_l, const int* __restrict__ toff_l,
                     const int* __restrict__ tcnt_l, float* __restrict__ Al,
                     const double* __restrict__ packed, int* __restrict__ cnt,
                     float2* __restrict__ dis12, float2* __restrict__ self12,
                     const int* __restrict__ batch, int* __restrict__ gstart,
                     int* __restrict__ bsum,
                     const float* __restrict__ fcxrb, const float* __restrict__ bias0,
                     float* __restrict__ out0){
    __shared__ int sd[256];
    int bx = blockIdx.x;
    if (bx < NA){
        if (bx < NB*VG) dev_buildA(Wr1, bucket_g, toff_g, tcnt_g, Ag, SG, VG, bx);
        else dev_buildA(Wr2, bucket_l, toff_l, tcnt_l, Al, SL, VL, bx - NB*VG);
        return;
    }
    bx -= NA;
    int t = threadIdx.x;
    if (bx == 49){
        for (int idx = t; idx < NB*128; idx += 256)
            out0[idx] = fcxrb[idx & 127] + bias0[idx & 127];
        return;
    }
    int base = bx*1024;
    int s = 0;
    #pragma unroll
    for (int j = 0; j < 4; ++j){
        int i = base + t*4 + j;
        if (i < NN){
            double p = packed[i];
            int c = (int)(p * (1.0/1048576.0));
            float w = (float)(p - (double)c * 1048576.0);
            cnt[i] = c; s += c;
            float r1 = rsqrtf(w + 1.0f);
            float r2 = rsqrtf((float)c + 1.0f);
            dis12[i] = make_float2(r1, r2);
            self12[i] = make_float2(r1*r1, r2*r2);
            int pb = batch[i];
            int prev = (i == 0) ? -1 : batch[i-1];
            for (int g = prev + 1; g <= pb; ++g) gstart[g] = i;
            if (i == NN - 1){
                for (int g = pb + 1; g <= NG; ++g) gstart[g] = NN;
            }
        }
    }
    sd[t] = s; __syncthreads();
    for (int d = 128; d > 0; d >>= 1){
        if (t < d) sd[t] += sd[t+d];
        __syncthreads();
    }
    if (t == 0) bsum[bx] = sd[0];
}

// scan3 with inline cross-block prefix (bsum holds raw per-block sums)
__global__ void k_scan3(const int* __restrict__ cnt, const int* __restrict__ bsum,
                        int* __restrict__ offs){
    __shared__ int sd[256];
    __shared__ int sbase;
    int t = threadIdx.x;
    if (t == 0){
        int run = 0;
        for (int i = 0; i < blockIdx.x; ++i) run += bsum[i];
        sbase = run;
    }
    int base = blockIdx.x*1024;
    int loc[4]; int s = 0;
    #pragma unroll
    for (int j = 0; j < 4; ++j){
        int idx = base + t*4 + j;
        loc[j] = (idx < NN) ? cnt[idx] : 0;
        s += loc[j];
    }
    sd[t] = s; __syncthreads();
    for (int d = 1; d < 256; d <<= 1){
        int v = (t >= d) ? sd[t-d] : 0;
        __syncthreads();
        sd[t] += v;
        __syncthreads();
    }
    int run = sbase + (sd[t] - s);
    #pragma unroll
    for (int j = 0; j < 4; ++j){
        int idx = base + t*4 + j;
        if (idx < NN) offs[idx] = run;
        run += loc[j];
    }
}

// ---------------- F2: buildG FIRST, then scatter, then cast ----------------
// G row index matches buildA's k' = v*256 + o*8 + k.
__device__ void dev_buildG(float (*rows)[128], const float* __restrict__ emb,
                           const float* __restrict__ W, bf16* __restrict__ G,
                           int V, int q){
    int o = q / V, mt = q - o*V;      // M = 8V, one block = 8 consecutive m
    int t = threadIdx.x;              // 256
    int j = t & 127, half = t >> 7;
    int kk[4], vv[4];
    #pragma unroll
    for (int qq = 0; qq < 4; ++qq){
        int mm = half*4 + qq;
        int m = mt*8 + mm;
        int k = m / V, v = m - k*V;
        kk[qq] = k; vv[qq] = v;
        rows[mm][j] = emb[v*128 + j];
    }
    __syncthreads();
    float a0=0.f, a1=0.f, a2=0.f, a3=0.f;
    const float* Wo = W + o*121*128 + j;
    for (int l = 0; l < 121; ++l){
        float w = Wo[l*128];
        a0 += rows[half*4+0][l + kk[0]] * w;
        a1 += rows[half*4+1][l + kk[1]] * w;
        a2 += rows[half*4+2][l + kk[2]] * w;
        a3 += rows[half*4+3][l + kk[3]] * w;
    }
    float a[4] = {a0, a1, a2, a3};
    #pragma unroll
    for (int qq = 0; qq < 4; ++qq){
        int row = vv[qq]*256 + o*8 + kk[qq];
        G[(size_t)row*128 + j] = __float2bfloat16(a[qq]);
    }
}

// epA record: {src index (int bits), norm layer 1}; epB: {src, norm layers 2/3}
__global__ void k_F2(const int* __restrict__ src, const int* __restrict__ dst,
                     const float* __restrict__ ew, const float2* __restrict__ dis12,
                     const int* __restrict__ offs, const int* __restrict__ slot,
                     float2* __restrict__ epA, float2* __restrict__ epB,
                     const float* __restrict__ emb1, const float* __restrict__ emb2,
                     const float* __restrict__ fcxrW, bf16* __restrict__ G1,
                     bf16* __restrict__ G2,
                     const float* __restrict__ pro_x, bf16* __restrict__ xb0){
    __shared__ float rows[8][128];
    int bx = blockIdx.x;
    if (bx < 32*VG){ dev_buildG(rows, emb1, fcxrW, G1, VG, bx); return; }
    if (bx < NGB){ dev_buildG(rows, emb2, fcxrW, G2, VL, bx - 32*VG); return; }
    bx -= NGB;
    if (bx < EDB){
        int e = bx*256 + threadIdx.x;
        int s = src[e], d = dst[e];
        int pos = offs[d] + slot[e];
        float2 a = dis12[s], b = dis12[d];
        epA[pos] = make_float2(__int_as_float(s), a.x * ew[e] * b.x);
        epB[pos] = make_float2(__int_as_float(s), a.y * b.y);
        return;
    }
    bx -= EDB;
    int i = bx*256 + threadIdx.x;     // cast pro_x -> padded bf16 [NN,40]
    if (i >= NN*40) return;
    int n = i / 40, f = i - n*40;
    xb0[i] = __float2bfloat16(f < 33 ? pro_x[n*33 + f] : 0.f);
}

// ---------------- fused aggregate + GEMM (uint4 rows) ----------------
// Round-2 loop body (empirically the best of lane-util/prefetch/stripe
// variants — do not re-touch). Edge records are 8B {src, norm}; byte offsets
// reconstructed as src*STRIDE (one mul_u24). Predicated parallel tail.
// BN partial stats fused into the epilogue (64-way strided atomics).
template<int QV, int GRP, int STRIDE, int SZ>
__device__ void dev_agg(float* sAgg /* [4][QV*8] */,
                        const bf16* __restrict__ xb, const float2* __restrict__ ep,
                        const int* __restrict__ offs, const int* __restrict__ cnt,
                        const float2* __restrict__ self12,
                        const float* __restrict__ W, const float* __restrict__ bias,
                        float* __restrict__ tout, float* __restrict__ bnpart,
                        int F, int OF, int bx){
    const int LPG = 64 / GRP;
    int wave = threadIdx.x >> 6;
    int node = bx*4 + wave;
    int lane = threadIdx.x & 63;
    int grp  = lane / LPG;
    int gl   = lane % LPG;
    bool act = gl < QV;
    const char* xc = (const char*)xb;
    float a0=0,a1=0,a2=0,a3=0,a4=0,a5=0,a6=0,a7=0;
    int b = offs[node], e = b + cnt[node];
    if (act){
        int fo = gl << 4;   // lane byte offset within row
        if (grp == 0){
            float2 sw2 = self12[node];
            float sw = SZ ? sw2.y : sw2.x;
            uint4 u = *(const uint4*)(xc + node*(QV*16) + fo);
            a0 = sw*blo(u.x); a1 = sw*bhi(u.x); a2 = sw*blo(u.y); a3 = sw*bhi(u.y);
            a4 = sw*blo(u.z); a5 = sw*bhi(u.z); a6 = sw*blo(u.w); a7 = sw*bhi(u.w);
        }
        int p = b + grp;
        for (; p + 3*GRP < e; p += 4*GRP){
            float2 e0 = ep[p];
            float2 e1 = ep[p +   GRP];
            float2 e2 = ep[p + 2*GRP];
            float2 e3 = ep[p + 3*GRP];
            int o0 = __float_as_int(e0.x)*STRIDE; float n0 = e0.y;
            int o1 = __float_as_int(e1.x)*STRIDE; float n1 = e1.y;
            int o2 = __float_as_int(e2.x)*STRIDE; float n2 = e2.y;
            int o3 = __float_as_int(e3.x)*STRIDE; float n3 = e3.y;
            uint4 u0 = *(const uint4*)(xc + o0 + fo);
            uint4 u1 = *(const uint4*)(xc + o1 + fo);
            uint4 u2 = *(const uint4*)(xc + o2 + fo);
            uint4 u3 = *(const uint4*)(xc + o3 + fo);
            a0 += n0*blo(u0.x); a1 += n0*bhi(u0.x); a2 += n0*blo(u0.y); a3 += n0*bhi(u0.y);
            a4 += n0*blo(u0.z); a5 += n0*bhi(u0.z); a6 += n0*blo(u0.w); a7 += n0*bhi(u0.w);
            a0 += n1*blo(u1.x); a1 += n1*bhi(u1.x); a2 += n1*blo(u1.y); a3 += n1*bhi(u1.y);
            a4 += n1*blo(u1.z); a5 += n1*bhi(u1.z); a6 += n1*blo(u1.w); a7 += n1*bhi(u1.w);
            a0 += n2*blo(u2.x); a1 += n2*bhi(u2.x); a2 += n2*blo(u2.y); a3 += n2*bhi(u2.y);
            a4 += n2*blo(u2.z); a5 += n2*bhi(u2.z); a6 += n2*blo(u2.w); a7 += n2*bhi(u2.w);
            a0 += n3*blo(u3.x); a1 += n3*bhi(u3.x); a2 += n3*blo(u3.y); a3 += n3*bhi(u3.y);
            a4 += n3*blo(u3.z); a5 += n3*bhi(u3.z); a6 += n3*blo(u3.w); a7 += n3*bhi(u3.w);
        }
        if (p < e){   // predicated tail, <= 3 edges per group
            int p1 = p + GRP, p2 = p + 2*GRP;
            bool v1 = p1 < e, v2 = p2 < e;
            float2 e0 = ep[p];
            float2 e1 = ep[v1 ? p1 : p];
            float2 e2 = ep[v2 ? p2 : p];
            int o0 = __float_as_int(e0.x)*STRIDE;
            int o1 = __float_as_int(e1.x)*STRIDE;
            int o2 = __float_as_int(e2.x)*STRIDE;
            float n0 = e0.y;
            float n1 = v1 ? e1.y : 0.f;
            float n2 = v2 ? e2.y : 0.f;
            uint4 u0 = *(const uint4*)(xc + o0 + fo);
            uint4 u1 = *(const uint4*)(xc + o1 + fo);
            uint4 u2 = *(const uint4*)(xc + o2 + fo);
            a0 += n0*blo(u0.x); a1 += n0*bhi(u0.x); a2 += n0*blo(u0.y); a3 += n0*bhi(u0.y);
            a4 += n0*blo(u0.z); a5 += n0*bhi(u0.z); a6 += n0*blo(u0.w); a7 += n0*bhi(u0.w);
            a0 += n1*blo(u1.x); a1 += n1*bhi(u1.x); a2 += n1*blo(u1.y); a3 += n1*bhi(u1.y);
            a4 += n1*blo(u1.z); a5 += n1*bhi(u1.z); a6 += n1*blo(u1.w); a7 += n1*bhi(u1.w);
            a0 += n2*blo(u2.x); a1 += n2*bhi(u2.x); a2 += n2*blo(u2.y); a3 += n2*bhi(u2.y);
            a4 += n2*blo(u2.z); a5 += n2*bhi(u2.z); a6 += n2*blo(u2.w); a7 += n2*bhi(u2.w);
        }
    }
    #pragma unroll
    for (int m = LPG; m < 64; m <<= 1){
        a0 += __shfl_xor(a0, m); a1 += __shfl_xor(a1, m);
        a2 += __shfl_xor(a2, m); a3 += __shfl_xor(a3, m);
        a4 += __shfl_xor(a4, m); a5 += __shfl_xor(a5, m);
        a6 += __shfl_xor(a6, m); a7 += __shfl_xor(a7, m);
    }
    if (act && grp == 0){
        float4* dst = (float4*)&sAgg[wave*(QV*8) + gl*8];
        dst[0] = make_float4(a0, a1, a2, a3);
        dst[1] = make_float4(a4, a5, a6, a7);
    }
    __syncthreads();
    int i0 = bx*4;
    int j = threadIdx.x;
    if (j < OF){
        float c0 = bias[j], c1 = c0, c2 = c0, c3 = c0;
        const float* Wj = W + j;
        const float* s0 = sAgg;
        const float* s1 = sAgg + QV*8;
        const float* s2 = sAgg + 2*QV*8;
        const float* s3 = sAgg + 3*QV*8;
        #pragma unroll 4
        for (int f = 0; f < F; ++f){
            float w = Wj[f*OF];
            c0 += s0[f]*w; c1 += s1[f]*w; c2 += s2[f]*w; c3 += s3[f]*w;
        }
        tout[(size_t)(i0+0)*OF + j] = c0;
        tout[(size_t)(i0+1)*OF + j] = c1;
        tout[(size_t)(i0+2)*OF + j] = c2;
        tout[(size_t)(i0+3)*OF + j] = c3;
        // fused BN partial stats (64-way strided to dodge contention)
        float s  = c0 + c1 + c2 + c3;
        float ss = c0*c0 + c1*c1 + c2*c2 + c3*c3;
        float* part = bnpart + (bx & 63)*(2*OF);
        unsafeAtomicAdd(&part[j], s);
        unsafeAtomicAdd(&part[OF + j], ss);
    }
}

template<int QV, int GRP, int STRIDE, int SZ>
__global__ __launch_bounds__(256, 8)
void k_agg_gemm(const bf16* __restrict__ xb, const float2* __restrict__ ep,
                const int* __restrict__ offs, const int* __restrict__ cnt,
                const float2* __restrict__ self12,
                const float* __restrict__ W, const float* __restrict__ bias,
                float* __restrict__ tout, float* __restrict__ bnpart,
                int F, int OF){
    __shared__ float sAgg[4*QV*8];
    dev_agg<QV,GRP,STRIDE,SZ>(sAgg, xb, ep, offs, cnt, self12, W, bias,
                              tout, bnpart, F, OF, blockIdx.x);
}

// gemmR for 256 threads: 8 b-rows x 256-K slice, atomic epilogue
__device__ void dev_gemmR(float* xs /* [8][256] */, int bq,
                          const float* __restrict__ Ag, const bf16* __restrict__ G1,
                          const float* __restrict__ Al, const bf16* __restrict__ G2,
                          float* __restrict__ out0){
    int kpart = bq >> 4;       // 0..69
    int bgrp  = bq & 15;
    const float* X; const bf16* G; int K, k0;
    if (kpart < 5){ X = Ag; G = G1; K = 1280;  k0 = kpart*256; }
    else          { X = Al; G = G2; K = 16640; k0 = (kpart-5)*256; }
    int b0 = bgrp*8;
    int t = threadIdx.x;
    #pragma unroll
    for (int i = 0; i < 8; ++i)
        xs[i*256 + t] = X[(b0+i)*K + k0 + t];
    __syncthreads();
    int rq = t >> 7, j = t & 127;
    const float* x0 = xs + (rq*4)*256;
    float a0=0,a1=0,a2=0,a3=0;
    const bf16* Gp = G + (size_t)k0*128 + j;
    for (int kk = 0; kk < 256; ++kk){
        float g = b2f(Gp[kk*128]);
        a0 += x0[kk]*g; a1 += x0[256+kk]*g; a2 += x0[512+kk]*g; a3 += x0[768+kk]*g;
    }
    unsafeAtomicAdd(&out0[(b0+rq*4+0)*128 + j], 0.5f*a0);
    unsafeAtomicAdd(&out0[(b0+rq*4+1)*128 + j], 0.5f*a1);
    unsafeAtomicAdd(&out0[(b0+rq*4+2)*128 + j], 0.5f*a2);
    unsafeAtomicAdd(&out0[(b0+rq*4+3)*128 + j], 0.5f*a3);
}

// L3 aggregate+gemm  U  gemmR (RNA head backfills L3's latency stalls)
__global__ void k_L3(const bf16* __restrict__ xb, const float2* __restrict__ ep,
                     const int* __restrict__ offs, const int* __restrict__ cnt,
                     const float2* __restrict__ self12,
                     const float* __restrict__ W, const float* __restrict__ bias,
                     float* __restrict__ tout, float* __restrict__ bnpart,
                     const float* __restrict__ Ag, const bf16* __restrict__ G1,
                     const float* __restrict__ Al, const bf16* __restrict__ G2,
                     float* __restrict__ out0){
    __shared__ float smem[8*256];
    int bx = blockIdx.x;
    if (bx < AGB){
        dev_agg<9,4,144,1>(smem, xb, ep, offs, cnt, self12, W, bias, tout, bnpart,
                           66, 132, bx);
    } else {
        dev_gemmR(smem, bx - AGB, Ag, G1, Al, G2, out0);
    }
}

// reduce 64-way strided BN partials -> sums (1 block)
__global__ void k_bn_fin(const float* __restrict__ part, float* __restrict__ sums, int OF){
    int tid = threadIdx.x;
    if (tid >= 2*OF) return;
    float s = 0.f;
    #pragma unroll 8
    for (int k = 0; k < 64; ++k) s += part[k*(2*OF) + tid];
    sums[tid] = s;
}

// fused finalize+apply, flattened; padded bf16 out (stride OS)
__global__ void k_bn_apply(const float* __restrict__ t, const float* __restrict__ sums,
                           const float* __restrict__ g, const float* __restrict__ b,
                           bf16* __restrict__ xo, int OF, int OS, int total){
    int id = blockIdx.x*256 + threadIdx.x;
    if (id >= total) return;
    int i = id / OS, f = id - i*OS;
    float v = 0.f;
    if (f < OF){
        float m  = sums[f] * (1.0f/(float)NN);
        float vr = sums[OF + f] * (1.0f/(float)NN) - m*m;
        float sc = g[f] * rsqrtf(vr + 1e-5f);
        float sh = b[f] - m*sc;
        v = t[(size_t)i*OF + f] * sc + sh;
        v = v > 0.f ? v : 0.f;
    }
    xo[id] = __float2bfloat16(v);
}

// fused BN3-apply + pool + fcg1 + fcg2: block g does everything for graph g
// (reads finalized bnsum3 -> no extra atomic contention)
__global__ void k_fcgF(const float* __restrict__ bufB, const float* __restrict__ sums,
                       const float* __restrict__ bn3g, const float* __restrict__ bn3b,
                       const int* __restrict__ gstart,
                       const float* __restrict__ W1, const float* __restrict__ b1,
                       const float* __restrict__ W2, const float* __restrict__ b2,
                       float* __restrict__ out){
    __shared__ float scs[132], shs[132];
    __shared__ float pp[7][132];
    __shared__ float pr[132];
    __shared__ float hr[1024];
    __shared__ float part[8][128];
    int g = blockIdx.x, t = threadIdx.x;   // 1024
    if (t < 132){
        float m  = sums[t] * (1.0f/(float)NN);
        float vr = sums[132 + t] * (1.0f/(float)NN) - m*m;
        float sc = bn3g[t] * rsqrtf(vr + 1e-5f);
        scs[t] = sc;
        shs[t] = bn3b[t] - m*sc;
    }
    __syncthreads();
    int i0 = gstart[g], i1 = gstart[g+1];
    int r = t / 132, f = t - r*132;
    if (r < 7){
        float acc = 0.f;
        for (int i = i0 + r; i < i1; i += 7){
            float v = bufB[(size_t)i*132 + f] * scs[f] + shs[f];
            acc += v > 0.f ? v : 0.f;
        }
        pp[r][f] = acc;
    }
    __syncthreads();
    if (t < 132){
        float s = 0.f;
        #pragma unroll
        for (int k = 0; k < 7; ++k) s += pp[k][t];
        float inv = 1.0f / fmaxf((float)(i1 - i0), 1.0f);
        pr[t] = s * inv;
    }
    __syncthreads();
    float acc = b1[t];
    #pragma unroll 4
    for (int ff = 0; ff < 132; ++ff) acc += pr[ff] * W1[ff*1024 + t];
    hr[t] = acc > 0.f ? acc : 0.f;
    __syncthreads();
    int ks = t >> 7, j = t & 127;
    const float* Wp = W2 + (ks*128)*128 + j;
    const float* hp = hr + ks*128;
    float a = 0.f;
    #pragma unroll 8
    for (int kk = 0; kk < 128; ++kk) a += hp[kk] * Wp[(size_t)kk*128];
    part[ks][j] = a;
    __syncthreads();
    if (t < 128){
        float s = b2[t];
        #pragma unroll
        for (int rr = 0; rr < 8; ++rr) s += part[rr][t];
        out[g*128 + t] = s;
    }
}

extern "C" void kernel_launch(void* const* d_in, const int* in_sizes, int n_in,
                              void* d_out, int out_size, void* d_ws, size_t ws_size,
                              hipStream_t stream)
{
    (void)in_sizes; (void)n_in; (void)out_size; (void)ws_size;

    const float* pro_x  = (const float*)d_in[0];
    const int*   eidx   = (const int*)  d_in[1];
    const float* ew     = (const float*)d_in[2];
    const int*   pbatch = (const int*)  d_in[3];
    const int*   rna_g  = (const int*)  d_in[4];
    const int*   rna_l  = (const int*)  d_in[5];
    const float* emb1   = (const float*)d_in[6];
    const float* emb2   = (const float*)d_in[7];
    const float* convW1 = (const float*)d_in[8];
    const float* convb1 = (const float*)d_in[9];
    const float* convW2 = (const float*)d_in[10];
    const float* convb2 = (const float*)d_in[11];
    const float* fcxrW  = (const float*)d_in[12];
    const float* fcxrb  = (const float*)d_in[13];
    const float* g1W = (const float*)d_in[14];
    const float* g1b = (const float*)d_in[15];
    const float* g2W = (const float*)d_in[16];
    const float* g2b = (const float*)d_in[17];
    const float* g3W = (const float*)d_in[18];
    const float* g3b = (const float*)d_in[19];
    const float* bn1g = (const float*)d_in[20];
    const float* bn1b = (const float*)d_in[21];
    const float* bn2g = (const float*)d_in[22];
    const float* bn2b = (const float*)d_in[23];
    const float* bn3g = (const float*)d_in[24];
    const float* bn3b = (const float*)d_in[25];
    const float* fcg1W = (const float*)d_in[26];
    const float* fcg1b = (const float*)d_in[27];
    const float* fcg2W = (const float*)d_in[28];
    const float* fcg2b = (const float*)d_in[29];

    const int* e_src = eidx;
    const int* e_dst = eidx + NE;

    char* base = (char*)d_ws;
    size_t off = 0;
    auto alloc = [&](size_t bytes)->char*{
        off = (off + 255) & ~(size_t)255;
        char* p = base + off; off += bytes; return p;
    };

    // ---- zero zone (single memset) ----
    double* packed  = (double*)alloc(NN*8);
    float* bnsum1  = (float*)alloc(2*33*4);
    float* bnsum2  = (float*)alloc(2*66*4);
    float* bnsum3  = (float*)alloc(2*132*4);
    float* bias0   = (float*)alloc(128*4);
    float* bnpart1 = (float*)alloc(64*2*33*4);
    float* bnpart2 = (float*)alloc(64*2*66*4);
    float* bnpart3 = (float*)alloc(64*2*132*4);
    size_t zero_bytes = (off + 255) & ~(size_t)255;

    // ---- persistent buffers ----
    int*    cnt    = (int*)   alloc(NN*4);
    float2* dis12  = (float2*)alloc(NN*8);
    float2* self12 = (float2*)alloc(NN*8);
    int*    offs   = (int*)   alloc(NN*4);
    int*    bsum   = (int*)   alloc(64*4);
    int*    gstart = (int*)   alloc((NG+1)*4);
    float2* epA    = (float2*)alloc((size_t)NE*8);
    float2* epB    = (float2*)alloc((size_t)NE*8);
    float*  bufB   = (float*) alloc((size_t)NN*132*4);   // t (max OF=132)
    bf16*   xbA    = (bf16*)  alloc((size_t)NE*4);       // >= max(slot 6.4MB, NN*40*2)
    bf16*   xbB    = (bf16*)  alloc((size_t)NN*72*2);    // stride-72 features
    float*  Ag     = (float*) alloc((size_t)NB*256*VG*4);   // persistent: read by k_L3
    float*  Al     = (float*) alloc((size_t)NB*256*VL*4);
    bf16*   G1     = (bf16*)  alloc((size_t)32*8*VG*128*2);
    bf16*   G2     = (bf16*)  alloc((size_t)32*8*VL*128*2);

    // slot aliases xbA (consumed by F2 scatter before L1 bn_apply writes xbA)
    int*  slot = (int*)xbA;
    // xb0 (stride-40 cast, 4MB) aliases xbB (first written by L2 bn_apply)
    bf16* xb0  = (bf16*)xbB;

    float* out0 = (float*)d_out;          // xc_rna
    float* out1 = (float*)d_out + 16384;  // xp_out

    // ---- RNA scratch aliased onto bufB (consumed by k_front/F1/F2,
    // which complete before L1 agg_gemm writes bufB) ----
    char* rb = (char*)bufB;
    size_t ro = 0;
    auto ralloc = [&](size_t bytes)->char*{
        ro = (ro + 255) & ~(size_t)255;
        char* p = rb + ro; ro += bytes; return p;
    };
    int* toff_g   = (int*)ralloc(NB*VG*4);
    int* toff_l   = (int*)ralloc(NB*VL*4);
    int* tcnt_g   = (int*)ralloc(NB*VG*4);
    int* tcnt_l   = (int*)ralloc(NB*VL*4);
    u16* bucket_g = (u16*)ralloc((size_t)NB*SG*2);
    u16* bucket_l = (u16*)ralloc((size_t)NB*SL*2);
    float* Wr1    = (float*)ralloc((size_t)SG*256*4);
    float* Wr2    = (float*)ralloc((size_t)SL*256*4);

    hipMemsetAsync(d_ws, 0, zero_bytes, stream);

    // ---- front: bucketing U edge_deg U transposeW U bias0_acc ----
    k_front<<<2*NB + EDB + SG + SL + 32, 256, 0, stream>>>(
        rna_g, rna_l, tcnt_g, toff_g, bucket_g, tcnt_l, toff_l, bucket_l,
        convW1, convW2, Wr1, Wr2, fcxrW, convb1, convb2, bias0,
        e_dst, ew, packed, slot);

    // ---- F1: buildA (coalesced A layout) + folded prep/out0-init ----
    k_F1<<<NA + 50, 256, 0, stream>>>(Wr1, Wr2,
                                      bucket_g, toff_g, tcnt_g, Ag,
                                      bucket_l, toff_l, tcnt_l, Al,
                                      packed, cnt, dis12, self12, pbatch, gstart,
                                      bsum, fcxrb, bias0, out0);
    k_scan3<<<49, 256, 0, stream>>>(cnt, bsum, offs);

    // ---- F2: buildG first, then edge scatter (split 8B records), then cast ----
    k_F2<<<NGB + EDB + CASTB, 256, 0, stream>>>(
        e_src, e_dst, ew, dis12, offs, slot, epA, epB,
        emb1, emb2, fcxrW, G1, G2, pro_x, xb0);

    // ---- GCN layer 1 (33 -> 33), input stride 40 ----
    k_agg_gemm<5,8,80,0><<<AGB, 256, 0, stream>>>(xb0, epA, offs, cnt, self12,
                                                  g1W, g1b, bufB, bnpart1, 33, 33);
    k_bn_fin<<<1, 512, 0, stream>>>(bnpart1, bnsum1, 33);
    k_bn_apply<<<(NN*40+255)/256, 256, 0, stream>>>(bufB, bnsum1, bn1g, bn1b,
                                                    xbA, 33, 40, NN*40);

    // ---- GCN layer 2 (33 -> 66), input stride 40 (xbA), output stride 72 ----
    k_agg_gemm<5,8,80,1><<<AGB, 256, 0, stream>>>(xbA, epB, offs, cnt, self12,
                                                  g2W, g2b, bufB, bnpart2, 33, 66);
    k_bn_fin<<<1, 512, 0, stream>>>(bnpart2, bnsum2, 66);
    k_bn_apply<<<(NN*72+255)/256, 256, 0, stream>>>(bufB, bnsum2, bn2g, bn2b,
                                                    xbB, 66, 72, NN*72);

    // ---- GCN layer 3 (66 -> 132)  U  RNA-head gemmR ----
    k_L3<<<AGB + 1120, 256, 0, stream>>>(xbB, epB, offs, cnt, self12,
                                         g3W, g3b, bufB, bnpart3, Ag, G1, Al, G2, out0);
    k_bn_fin<<<1, 512, 0, stream>>>(bnpart3, bnsum3, 132);

    // ---- fused BN3-apply + pool + fcg1 + fcg2 ----
    k_fcgF<<<NG, 1024, 0, stream>>>(bufB, bnsum3, bn3g, bn3b, gstart,
                                    fcg1W, fcg1b, fcg2W, fcg2b, out1);
}

// Round 8
// 576.941 us; speedup vs baseline: 1.0304x; 1.0304x over previous
//
#include <hip/hip_runtime.h>
#include <hip/hip_bf16.h>

typedef __hip_bfloat16 bf16;
typedef unsigned short u16;

#define NN 50000      // nodes
#define NE 1600000    // edges (= 6250*256 exactly)
#define NG 128        // graphs
#define NB 128        // rna batch
#define SG 3000       // global seq (channels)
#define SL 2998       // local seq
#define VG 5          // global vocab
#define VL 65         // local vocab
#define EDB 6250      // edge blocks (NE/256)
#define AGB 12500     // agg blocks (NN/4)
#define NA  (NB*VG + NB*VL)   // 1490 buildA blocks
#define NGB (32*VG + 32*VL)   // 2240 buildG blocks
#define CASTB ((NN*40+255)/256)  // 7813

__device__ __forceinline__ float b2f(bf16 x){ return __bfloat162float(x); }
__device__ __forceinline__ float blo(unsigned u){ return __uint_as_float(u << 16); }
__device__ __forceinline__ float bhi(unsigned u){ return __uint_as_float(u & 0xffff0000u); }

// ---------------- buildG (runs inside k_front) -----------------------------
// G row index matches buildA's k' = v*256 + o*8 + k.
__device__ void dev_buildG(float (*rows)[128], const float* __restrict__ emb,
                           const float* __restrict__ W, bf16* __restrict__ G,
                           int V, int q){
    int o = q / V, mt = q - o*V;      // M = 8V, one block = 8 consecutive m
    int t = threadIdx.x;              // 256
    int j = t & 127, half = t >> 7;
    int kk[4], vv[4];
    #pragma unroll
    for (int qq = 0; qq < 4; ++qq){
        int mm = half*4 + qq;
        int m = mt*8 + mm;
        int k = m / V, v = m - k*V;
        kk[qq] = k; vv[qq] = v;
        rows[mm][j] = emb[v*128 + j];
    }
    __syncthreads();
    float a0=0.f, a1=0.f, a2=0.f, a3=0.f;
    const float* Wo = W + o*121*128 + j;
    for (int l = 0; l < 121; ++l){
        float w = Wo[l*128];
        a0 += rows[half*4+0][l + kk[0]] * w;
        a1 += rows[half*4+1][l + kk[1]] * w;
        a2 += rows[half*4+2][l + kk[2]] * w;
        a3 += rows[half*4+3][l + kk[3]] * w;
    }
    float a[4] = {a0, a1, a2, a3};
    #pragma unroll
    for (int qq = 0; qq < 4; ++qq){
        int row = vv[qq]*256 + o*8 + kk[qq];
        G[(size_t)row*128 + j] = __float2bfloat16(a[qq]);
    }
}

// ------- k_front: bucketing U buildG U edge_deg U transposeW U cast U bias0
// buildG (VALU-dense) and cast (small stream) are dependency-free; they
// backfill the bucketing (LDS) and edge_deg (fabric atomic) stalls with
// orthogonal resources.
__global__ void k_front(const int* __restrict__ rna_g, const int* __restrict__ rna_l,
                        int* __restrict__ tcnt_g, int* __restrict__ toff_g,
                        u16* __restrict__ bucket_g,
                        int* __restrict__ tcnt_l, int* __restrict__ toff_l,
                        u16* __restrict__ bucket_l,
                        const float* __restrict__ convW1, const float* __restrict__ convW2,
                        bf16* __restrict__ Wr1, bf16* __restrict__ Wr2,
                        const float* __restrict__ fcxrW, const float* __restrict__ cb1,
                        const float* __restrict__ cb2, float* __restrict__ bias0,
                        const int* __restrict__ dst, const float* __restrict__ ew,
                        double* __restrict__ packed, int* __restrict__ slot,
                        const float* __restrict__ emb1, const float* __restrict__ emb2,
                        bf16* __restrict__ G1, bf16* __restrict__ G2,
                        const float* __restrict__ pro_x, bf16* __restrict__ xb0){
    __shared__ int hist[VL], pre[VL], cur[VL];
    __shared__ float rows[8][128];
    int bx = blockIdx.x;
    int t = threadIdx.x;
    if (bx < 2*NB){
        int br = bx & 1, b = bx >> 1;
        const int* tok = br ? rna_l : rna_g;
        int S = br ? SL : SG, V = br ? VL : VG;
        int* tcnt = br ? tcnt_l : tcnt_g;
        int* toff = br ? toff_l : toff_g;
        u16* bucket = br ? bucket_l : bucket_g;
        if (t < V) hist[t] = 0;
        __syncthreads();
        for (int i = t; i < S; i += 256) atomicAdd(&hist[tok[b*S + i]], 1);
        __syncthreads();
        if (t == 0){
            int run = 0;
            for (int v = 0; v < V; ++v){ pre[v] = run; run += hist[v]; }
        }
        __syncthreads();
        if (t < V){
            tcnt[b*V + t] = hist[t];
            toff[b*V + t] = pre[t];
            cur[t] = pre[t];
        }
        __syncthreads();
        for (int i = t; i < S; i += 256){
            int v = tok[b*S + i];
            int p = atomicAdd(&cur[v], 1);
            bucket[b*S + p] = (u16)i;
        }
        return;
    }
    bx -= 2*NB;
    if (bx < NGB){
        if (bx < 32*VG) dev_buildG(rows, emb1, fcxrW, G1, VG, bx);
        else dev_buildG(rows, emb2, fcxrW, G2, VL, bx - 32*VG);
        return;
    }
    bx -= NGB;
    if (bx < EDB){
        int e = bx*256 + t;
        double old = unsafeAtomicAdd(&packed[dst[e]], 1048576.0 + (double)ew[e]);
        slot[e] = (int)(old * (1.0/1048576.0));
        return;
    }
    bx -= EDB;
    if (bx < SG + SL){
        const float* W; bf16* Wr; int S, c = bx;
        if (c < SG){ W = convW1; Wr = Wr1; S = SG; }
        else { c -= SG; W = convW2; Wr = Wr2; S = SL; }
        Wr[c*256 + t] = __float2bfloat16(W[((t >> 3)*S + c)*8 + (t & 7)]);
        return;
    }
    bx -= SG + SL;
    if (bx < CASTB){
        int i = bx*256 + t;           // cast pro_x -> padded bf16 [NN,40]
        if (i >= NN*40) return;
        int n = i / 40, f = i - n*40;
        xb0[i] = __float2bfloat16(f < 33 ? pro_x[n*33 + f] : 0.f);
        return;
    }
    bx -= CASTB;
    if (t >= 128) return;
    int o = bx, j = t;
    float s = 0.f;
    const float* Wo = fcxrW + o*121*128 + j;
    for (int l = 0; l < 121; ++l) s += Wo[l*128];
    unsafeAtomicAdd(&bias0[j], 0.5f * (cb1[o] + cb2[o]) * s);
}

// ---------------- buildA: K index k' = v*256 + t  (coalesced store) --------
// Wr is bf16 (3 MB table -> fits per-XCD L2); accumulate fp32.
__device__ void dev_buildA(const bf16* __restrict__ Wr, const u16* __restrict__ bucket,
                           const int* __restrict__ toff, const int* __restrict__ tcnt,
                           float* __restrict__ A, int S, int V, int bv){
    int b = bv / V, v = bv - b*V;
    int t = threadIdx.x;            // t = o*8+k
    const u16* bk = bucket + b*S + toff[b*V + v];
    int m = tcnt[b*V + v];
    float acc = 0.f;
    int idx = 0;
    for (; idx + 4 <= m; idx += 4){
        int c0 = bk[idx], c1 = bk[idx+1], c2 = bk[idx+2], c3 = bk[idx+3];
        acc += b2f(Wr[c0*256 + t]);
        acc += b2f(Wr[c1*256 + t]);
        acc += b2f(Wr[c2*256 + t]);
        acc += b2f(Wr[c3*256 + t]);
    }
    for (; idx < m; ++idx) acc += b2f(Wr[bk[idx]*256 + t]);
    A[b*(256*V) + v*256 + t] = acc;   // contiguous in t: 1KB coalesced/block
}

// ---------------- F1: buildA (bf16 Wr) + prep + out0 init ------------------
__global__ void k_F1(const bf16* __restrict__ Wr1, const bf16* __restrict__ Wr2,
                     const u16* __restrict__ bucket_g, const int* __restrict__ toff_g,
                     const int* __restrict__ tcnt_g, float* __restrict__ Ag,
                     const u16* __restrict__ bucket_l, const int* __restrict__ toff_l,
                     const int* __restrict__ tcnt_l, float* __restrict__ Al,
                     const double* __restrict__ packed, int* __restrict__ cnt,
                     float2* __restrict__ dis12, float2* __restrict__ self12,
                     const int* __restrict__ batch, int* __restrict__ gstart,
                     int* __restrict__ bsum,
                     const float* __restrict__ fcxrb, const float* __restrict__ bias0,
                     float* __restrict__ out0){
    __shared__ int sd[256];
    int bx = blockIdx.x;
    if (bx < NA){
        if (bx < NB*VG) dev_buildA(Wr1, bucket_g, toff_g, tcnt_g, Ag, SG, VG, bx);
        else dev_buildA(Wr2, bucket_l, toff_l, tcnt_l, Al, SL, VL, bx - NB*VG);
        return;
    }
    bx -= NA;
    int t = threadIdx.x;
    if (bx == 49){
        for (int idx = t; idx < NB*128; idx += 256)
            out0[idx] = fcxrb[idx & 127] + bias0[idx & 127];
        return;
    }
    int base = bx*1024;
    int s = 0;
    #pragma unroll
    for (int j = 0; j < 4; ++j){
        int i = base + t*4 + j;
        if (i < NN){
            double p = packed[i];
            int c = (int)(p * (1.0/1048576.0));
            float w = (float)(p - (double)c * 1048576.0);
            cnt[i] = c; s += c;
            float r1 = rsqrtf(w + 1.0f);
            float r2 = rsqrtf((float)c + 1.0f);
            dis12[i] = make_float2(r1, r2);
            self12[i] = make_float2(r1*r1, r2*r2);
            int pb = batch[i];
            int prev = (i == 0) ? -1 : batch[i-1];
            for (int g = prev + 1; g <= pb; ++g) gstart[g] = i;
            if (i == NN - 1){
                for (int g = pb + 1; g <= NG; ++g) gstart[g] = NN;
            }
        }
    }
    sd[t] = s; __syncthreads();
    for (int d = 128; d > 0; d >>= 1){
        if (t < d) sd[t] += sd[t+d];
        __syncthreads();
    }
    if (t == 0) bsum[bx] = sd[0];
}

// scan3 with inline cross-block prefix (bsum holds raw per-block sums)
__global__ void k_scan3(const int* __restrict__ cnt, const int* __restrict__ bsum,
                        int* __restrict__ offs){
    __shared__ int sd[256];
    __shared__ int sbase;
    int t = threadIdx.x;
    if (t == 0){
        int run = 0;
        for (int i = 0; i < blockIdx.x; ++i) run += bsum[i];
        sbase = run;
    }
    int base = blockIdx.x*1024;
    int loc[4]; int s = 0;
    #pragma unroll
    for (int j = 0; j < 4; ++j){
        int idx = base + t*4 + j;
        loc[j] = (idx < NN) ? cnt[idx] : 0;
        s += loc[j];
    }
    sd[t] = s; __syncthreads();
    for (int d = 1; d < 256; d <<= 1){
        int v = (t >= d) ? sd[t-d] : 0;
        __syncthreads();
        sd[t] += v;
        __syncthreads();
    }
    int run = sbase + (sd[t] - s);
    #pragma unroll
    for (int j = 0; j < 4; ++j){
        int idx = base + t*4 + j;
        if (idx < NN) offs[idx] = run;
        run += loc[j];
    }
}

// ---------------- F2: edge scatter only (8B split records) -----------------
// epA record: {src index (int bits), norm layer 1}; epB: {src, norm layers 2/3}
__global__ void k_F2(const int* __restrict__ src, const int* __restrict__ dst,
                     const float* __restrict__ ew, const float2* __restrict__ dis12,
                     const int* __restrict__ offs, const int* __restrict__ slot,
                     float2* __restrict__ epA, float2* __restrict__ epB){
    int e = blockIdx.x*256 + threadIdx.x;
    int s = src[e], d = dst[e];
    int pos = offs[d] + slot[e];
    float2 a = dis12[s], b = dis12[d];
    epA[pos] = make_float2(__int_as_float(s), a.x * ew[e] * b.x);
    epB[pos] = make_float2(__int_as_float(s), a.y * b.y);
}

// ---------------- fused aggregate + GEMM (uint4 rows) ----------------
// Round-2 loop body (frozen — best of lane-util/prefetch/stripe variants).
// Edge records are 8B {src, norm}; byte offsets reconstructed as src*STRIDE.
// Predicated parallel tail. BN partial stats fused (64-way strided atomics).
template<int QV, int GRP, int STRIDE, int SZ>
__device__ void dev_agg(float* sAgg /* [4][QV*8] */,
                        const bf16* __restrict__ xb, const float2* __restrict__ ep,
                        const int* __restrict__ offs, const int* __restrict__ cnt,
                        const float2* __restrict__ self12,
                        const float* __restrict__ W, const float* __restrict__ bias,
                        float* __restrict__ tout, float* __restrict__ bnpart,
                        int F, int OF, int bx){
    const int LPG = 64 / GRP;
    int wave = threadIdx.x >> 6;
    int node = bx*4 + wave;
    int lane = threadIdx.x & 63;
    int grp  = lane / LPG;
    int gl   = lane % LPG;
    bool act = gl < QV;
    const char* xc = (const char*)xb;
    float a0=0,a1=0,a2=0,a3=0,a4=0,a5=0,a6=0,a7=0;
    int b = offs[node], e = b + cnt[node];
    if (act){
        int fo = gl << 4;   // lane byte offset within row
        if (grp == 0){
            float2 sw2 = self12[node];
            float sw = SZ ? sw2.y : sw2.x;
            uint4 u = *(const uint4*)(xc + node*(QV*16) + fo);
            a0 = sw*blo(u.x); a1 = sw*bhi(u.x); a2 = sw*blo(u.y); a3 = sw*bhi(u.y);
            a4 = sw*blo(u.z); a5 = sw*bhi(u.z); a6 = sw*blo(u.w); a7 = sw*bhi(u.w);
        }
        int p = b + grp;
        for (; p + 3*GRP < e; p += 4*GRP){
            float2 e0 = ep[p];
            float2 e1 = ep[p +   GRP];
            float2 e2 = ep[p + 2*GRP];
            float2 e3 = ep[p + 3*GRP];
            int o0 = __float_as_int(e0.x)*STRIDE; float n0 = e0.y;
            int o1 = __float_as_int(e1.x)*STRIDE; float n1 = e1.y;
            int o2 = __float_as_int(e2.x)*STRIDE; float n2 = e2.y;
            int o3 = __float_as_int(e3.x)*STRIDE; float n3 = e3.y;
            uint4 u0 = *(const uint4*)(xc + o0 + fo);
            uint4 u1 = *(const uint4*)(xc + o1 + fo);
            uint4 u2 = *(const uint4*)(xc + o2 + fo);
            uint4 u3 = *(const uint4*)(xc + o3 + fo);
            a0 += n0*blo(u0.x); a1 += n0*bhi(u0.x); a2 += n0*blo(u0.y); a3 += n0*bhi(u0.y);
            a4 += n0*blo(u0.z); a5 += n0*bhi(u0.z); a6 += n0*blo(u0.w); a7 += n0*bhi(u0.w);
            a0 += n1*blo(u1.x); a1 += n1*bhi(u1.x); a2 += n1*blo(u1.y); a3 += n1*bhi(u1.y);
            a4 += n1*blo(u1.z); a5 += n1*bhi(u1.z); a6 += n1*blo(u1.w); a7 += n1*bhi(u1.w);
            a0 += n2*blo(u2.x); a1 += n2*bhi(u2.x); a2 += n2*blo(u2.y); a3 += n2*bhi(u2.y);
            a4 += n2*blo(u2.z); a5 += n2*bhi(u2.z); a6 += n2*blo(u2.w); a7 += n2*bhi(u2.w);
            a0 += n3*blo(u3.x); a1 += n3*bhi(u3.x); a2 += n3*blo(u3.y); a3 += n3*bhi(u3.y);
            a4 += n3*blo(u3.z); a5 += n3*bhi(u3.z); a6 += n3*blo(u3.w); a7 += n3*bhi(u3.w);
        }
        if (p < e){   // predicated tail, <= 3 edges per group
            int p1 = p + GRP, p2 = p + 2*GRP;
            bool v1 = p1 < e, v2 = p2 < e;
            float2 e0 = ep[p];
            float2 e1 = ep[v1 ? p1 : p];
            float2 e2 = ep[v2 ? p2 : p];
            int o0 = __float_as_int(e0.x)*STRIDE;
            int o1 = __float_as_int(e1.x)*STRIDE;
            int o2 = __float_as_int(e2.x)*STRIDE;
            float n0 = e0.y;
            float n1 = v1 ? e1.y : 0.f;
            float n2 = v2 ? e2.y : 0.f;
            uint4 u0 = *(const uint4*)(xc + o0 + fo);
            uint4 u1 = *(const uint4*)(xc + o1 + fo);
            uint4 u2 = *(const uint4*)(xc + o2 + fo);
            a0 += n0*blo(u0.x); a1 += n0*bhi(u0.x); a2 += n0*blo(u0.y); a3 += n0*bhi(u0.y);
            a4 += n0*blo(u0.z); a5 += n0*bhi(u0.z); a6 += n0*blo(u0.w); a7 += n0*bhi(u0.w);
            a0 += n1*blo(u1.x); a1 += n1*bhi(u1.x); a2 += n1*blo(u1.y); a3 += n1*bhi(u1.y);
            a4 += n1*blo(u1.z); a5 += n1*bhi(u1.z); a6 += n1*blo(u1.w); a7 += n1*bhi(u1.w);
            a0 += n2*blo(u2.x); a1 += n2*bhi(u2.x); a2 += n2*blo(u2.y); a3 += n2*bhi(u2.y);
            a4 += n2*blo(u2.z); a5 += n2*bhi(u2.z); a6 += n2*blo(u2.w); a7 += n2*bhi(u2.w);
        }
    }
    #pragma unroll
    for (int m = LPG; m < 64; m <<= 1){
        a0 += __shfl_xor(a0, m); a1 += __shfl_xor(a1, m);
        a2 += __shfl_xor(a2, m); a3 += __shfl_xor(a3, m);
        a4 += __shfl_xor(a4, m); a5 += __shfl_xor(a5, m);
        a6 += __shfl_xor(a6, m); a7 += __shfl_xor(a7, m);
    }
    if (act && grp == 0){
        float4* dst = (float4*)&sAgg[wave*(QV*8) + gl*8];
        dst[0] = make_float4(a0, a1, a2, a3);
        dst[1] = make_float4(a4, a5, a6, a7);
    }
    __syncthreads();
    int i0 = bx*4;
    int j = threadIdx.x;
    if (j < OF){
        float c0 = bias[j], c1 = c0, c2 = c0, c3 = c0;
        const float* Wj = W + j;
        const float* s0 = sAgg;
        const float* s1 = sAgg + QV*8;
        const float* s2 = sAgg + 2*QV*8;
        const float* s3 = sAgg + 3*QV*8;
        #pragma unroll 4
        for (int f = 0; f < F; ++f){
            float w = Wj[f*OF];
            c0 += s0[f]*w; c1 += s1[f]*w; c2 += s2[f]*w; c3 += s3[f]*w;
        }
        tout[(size_t)(i0+0)*OF + j] = c0;
        tout[(size_t)(i0+1)*OF + j] = c1;
        tout[(size_t)(i0+2)*OF + j] = c2;
        tout[(size_t)(i0+3)*OF + j] = c3;
        // fused BN partial stats (64-way strided to dodge contention)
        float s  = c0 + c1 + c2 + c3;
        float ss = c0*c0 + c1*c1 + c2*c2 + c3*c3;
        float* part = bnpart + (bx & 63)*(2*OF);
        unsafeAtomicAdd(&part[j], s);
        unsafeAtomicAdd(&part[OF + j], ss);
    }
}

template<int QV, int GRP, int STRIDE, int SZ>
__global__ __launch_bounds__(256, 8)
void k_agg_gemm(const bf16* __restrict__ xb, const float2* __restrict__ ep,
                const int* __restrict__ offs, const int* __restrict__ cnt,
                const float2* __restrict__ self12,
                const float* __restrict__ W, const float* __restrict__ bias,
                float* __restrict__ tout, float* __restrict__ bnpart,
                int F, int OF){
    __shared__ float sAgg[4*QV*8];
    dev_agg<QV,GRP,STRIDE,SZ>(sAgg, xb, ep, offs, cnt, self12, W, bias,
                              tout, bnpart, F, OF, blockIdx.x);
}

// gemmR for 256 threads: 8 b-rows x 256-K slice, atomic epilogue
__device__ void dev_gemmR(float* xs /* [8][256] */, int bq,
                          const float* __restrict__ Ag, const bf16* __restrict__ G1,
                          const float* __restrict__ Al, const bf16* __restrict__ G2,
                          float* __restrict__ out0){
    int kpart = bq >> 4;       // 0..69
    int bgrp  = bq & 15;
    const float* X; const bf16* G; int K, k0;
    if (kpart < 5){ X = Ag; G = G1; K = 1280;  k0 = kpart*256; }
    else          { X = Al; G = G2; K = 16640; k0 = (kpart-5)*256; }
    int b0 = bgrp*8;
    int t = threadIdx.x;
    #pragma unroll
    for (int i = 0; i < 8; ++i)
        xs[i*256 + t] = X[(b0+i)*K + k0 + t];
    __syncthreads();
    int rq = t >> 7, j = t & 127;
    const float* x0 = xs + (rq*4)*256;
    float a0=0,a1=0,a2=0,a3=0;
    const bf16* Gp = G + (size_t)k0*128 + j;
    for (int kk = 0; kk < 256; ++kk){
        float g = b2f(Gp[kk*128]);
        a0 += x0[kk]*g; a1 += x0[256+kk]*g; a2 += x0[512+kk]*g; a3 += x0[768+kk]*g;
    }
    unsafeAtomicAdd(&out0[(b0+rq*4+0)*128 + j], 0.5f*a0);
    unsafeAtomicAdd(&out0[(b0+rq*4+1)*128 + j], 0.5f*a1);
    unsafeAtomicAdd(&out0[(b0+rq*4+2)*128 + j], 0.5f*a2);
    unsafeAtomicAdd(&out0[(b0+rq*4+3)*128 + j], 0.5f*a3);
}

// L3 aggregate+gemm  U  gemmR (RNA head backfills L3's latency stalls)
__global__ void k_L3(const bf16* __restrict__ xb, const float2* __restrict__ ep,
                     const int* __restrict__ offs, const int* __restrict__ cnt,
                     const float2* __restrict__ self12,
                     const float* __restrict__ W, const float* __restrict__ bias,
                     float* __restrict__ tout, float* __restrict__ bnpart,
                     const float* __restrict__ Ag, const bf16* __restrict__ G1,
                     const float* __restrict__ Al, const bf16* __restrict__ G2,
                     float* __restrict__ out0){
    __shared__ float smem[8*256];
    int bx = blockIdx.x;
    if (bx < AGB){
        dev_agg<9,4,144,1>(smem, xb, ep, offs, cnt, self12, W, bias, tout, bnpart,
                           66, 132, bx);
    } else {
        dev_gemmR(smem, bx - AGB, Ag, G1, Al, G2, out0);
    }
}

// reduce 64-way strided BN partials -> sums (1 block)
__global__ void k_bn_fin(const float* __restrict__ part, float* __restrict__ sums, int OF){
    int tid = threadIdx.x;
    if (tid >= 2*OF) return;
    float s = 0.f;
    #pragma unroll 8
    for (int k = 0; k < 64; ++k) s += part[k*(2*OF) + tid];
    sums[tid] = s;
}

// fused finalize+apply, flattened; padded bf16 out (stride OS)
__global__ void k_bn_apply(const float* __restrict__ t, const float* __restrict__ sums,
                           const float* __restrict__ g, const float* __restrict__ b,
                           bf16* __restrict__ xo, int OF, int OS, int total){
    int id = blockIdx.x*256 + threadIdx.x;
    if (id >= total) return;
    int i = id / OS, f = id - i*OS;
    float v = 0.f;
    if (f < OF){
        float m  = sums[f] * (1.0f/(float)NN);
        float vr = sums[OF + f] * (1.0f/(float)NN) - m*m;
        float sc = g[f] * rsqrtf(vr + 1e-5f);
        float sh = b[f] - m*sc;
        v = t[(size_t)i*OF + f] * sc + sh;
        v = v > 0.f ? v : 0.f;
    }
    xo[id] = __float2bfloat16(v);
}

// fused BN3-apply + pool + fcg1 + fcg2: block g does everything for graph g
// (reads finalized bnsum3 -> no extra atomic contention)
__global__ void k_fcgF(const float* __restrict__ bufB, const float* __restrict__ sums,
                       const float* __restrict__ bn3g, const float* __restrict__ bn3b,
                       const int* __restrict__ gstart,
                       const float* __restrict__ W1, const float* __restrict__ b1,
                       const float* __restrict__ W2, const float* __restrict__ b2,
                       float* __restrict__ out){
    __shared__ float scs[132], shs[132];
    __shared__ float pp[7][132];
    __shared__ float pr[132];
    __shared__ float hr[1024];
    __shared__ float part[8][128];
    int g = blockIdx.x, t = threadIdx.x;   // 1024
    if (t < 132){
        float m  = sums[t] * (1.0f/(float)NN);
        float vr = sums[132 + t] * (1.0f/(float)NN) - m*m;
        float sc = bn3g[t] * rsqrtf(vr + 1e-5f);
        scs[t] = sc;
        shs[t] = bn3b[t] - m*sc;
    }
    __syncthreads();
    int i0 = gstart[g], i1 = gstart[g+1];
    int r = t / 132, f = t - r*132;
    if (r < 7){
        float acc = 0.f;
        for (int i = i0 + r; i < i1; i += 7){
            float v = bufB[(size_t)i*132 + f] * scs[f] + shs[f];
            acc += v > 0.f ? v : 0.f;
        }
        pp[r][f] = acc;
    }
    __syncthreads();
    if (t < 132){
        float s = 0.f;
        #pragma unroll
        for (int k = 0; k < 7; ++k) s += pp[k][t];
        float inv = 1.0f / fmaxf((float)(i1 - i0), 1.0f);
        pr[t] = s * inv;
    }
    __syncthreads();
    float acc = b1[t];
    #pragma unroll 4
    for (int ff = 0; ff < 132; ++ff) acc += pr[ff] * W1[ff*1024 + t];
    hr[t] = acc > 0.f ? acc : 0.f;
    __syncthreads();
    int ks = t >> 7, j = t & 127;
    const float* Wp = W2 + (ks*128)*128 + j;
    const float* hp = hr + ks*128;
    float a = 0.f;
    #pragma unroll 8
    for (int kk = 0; kk < 128; ++kk) a += hp[kk] * Wp[(size_t)kk*128];
    part[ks][j] = a;
    __syncthreads();
    if (t < 128){
        float s = b2[t];
        #pragma unroll
        for (int rr = 0; rr < 8; ++rr) s += part[rr][t];
        out[g*128 + t] = s;
    }
}

extern "C" void kernel_launch(void* const* d_in, const int* in_sizes, int n_in,
                              void* d_out, int out_size, void* d_ws, size_t ws_size,
                              hipStream_t stream)
{
    (void)in_sizes; (void)n_in; (void)out_size; (void)ws_size;

    const float* pro_x  = (const float*)d_in[0];
    const int*   eidx   = (const int*)  d_in[1];
    const float* ew     = (const float*)d_in[2];
    const int*   pbatch = (const int*)  d_in[3];
    const int*   rna_g  = (const int*)  d_in[4];
    const int*   rna_l  = (const int*)  d_in[5];
    const float* emb1   = (const float*)d_in[6];
    const float* emb2   = (const float*)d_in[7];
    const float* convW1 = (const float*)d_in[8];
    const float* convb1 = (const float*)d_in[9];
    const float* convW2 = (const float*)d_in[10];
    const float* convb2 = (const float*)d_in[11];
    const float* fcxrW  = (const float*)d_in[12];
    const float* fcxrb  = (const float*)d_in[13];
    const float* g1W = (const float*)d_in[14];
    const float* g1b = (const float*)d_in[15];
    const float* g2W = (const float*)d_in[16];
    const float* g2b = (const float*)d_in[17];
    const float* g3W = (const float*)d_in[18];
    const float* g3b = (const float*)d_in[19];
    const float* bn1g = (const float*)d_in[20];
    const float* bn1b = (const float*)d_in[21];
    const float* bn2g = (const float*)d_in[22];
    const float* bn2b = (const float*)d_in[23];
    const float* bn3g = (const float*)d_in[24];
    const float* bn3b = (const float*)d_in[25];
    const float* fcg1W = (const float*)d_in[26];
    const float* fcg1b = (const float*)d_in[27];
    const float* fcg2W = (const float*)d_in[28];
    const float* fcg2b = (const float*)d_in[29];

    const int* e_src = eidx;
    const int* e_dst = eidx + NE;

    char* base = (char*)d_ws;
    size_t off = 0;
    auto alloc = [&](size_t bytes)->char*{
        off = (off + 255) & ~(size_t)255;
        char* p = base + off; off += bytes; return p;
    };

    // ---- zero zone (single memset) ----
    double* packed  = (double*)alloc(NN*8);
    float* bnsum1  = (float*)alloc(2*33*4);
    float* bnsum2  = (float*)alloc(2*66*4);
    float* bnsum3  = (float*)alloc(2*132*4);
    float* bias0   = (float*)alloc(128*4);
    float* bnpart1 = (float*)alloc(64*2*33*4);
    float* bnpart2 = (float*)alloc(64*2*66*4);
    float* bnpart3 = (float*)alloc(64*2*132*4);
    size_t zero_bytes = (off + 255) & ~(size_t)255;

    // ---- persistent buffers ----
    int*    cnt    = (int*)   alloc(NN*4);
    float2* dis12  = (float2*)alloc(NN*8);
    float2* self12 = (float2*)alloc(NN*8);
    int*    offs   = (int*)   alloc(NN*4);
    int*    bsum   = (int*)   alloc(64*4);
    int*    gstart = (int*)   alloc((NG+1)*4);
    float2* epA    = (float2*)alloc((size_t)NE*8);
    float2* epB    = (float2*)alloc((size_t)NE*8);
    float*  bufB   = (float*) alloc((size_t)NN*132*4);   // t (max OF=132)
    bf16*   xbA    = (bf16*)  alloc((size_t)NE*4);       // >= max(slot 6.4MB, NN*40*2)
    bf16*   xbB    = (bf16*)  alloc((size_t)NN*72*2);    // stride-72 features
    float*  Ag     = (float*) alloc((size_t)NB*256*VG*4);   // persistent: read by k_L3
    float*  Al     = (float*) alloc((size_t)NB*256*VL*4);
    bf16*   G1     = (bf16*)  alloc((size_t)32*8*VG*128*2);
    bf16*   G2     = (bf16*)  alloc((size_t)32*8*VL*128*2);
    // xb0 gets its own buffer now (written by k_front cast, read by agg1;
    // cannot alias xbB because front precedes both uses anyway, but keep
    // the proven aliasing: xb0 aliases xbB (first written by L2 bn_apply).
    // Order: front cast -> agg1 reads xb0 -> bn_apply2 overwrites xbB. Safe.

    // slot aliases xbA (consumed by F2 scatter before L1 bn_apply writes xbA)
    int*  slot = (int*)xbA;
    bf16* xb0  = (bf16*)xbB;

    float* out0 = (float*)d_out;          // xc_rna
    float* out1 = (float*)d_out + 16384;  // xp_out

    // ---- RNA scratch aliased onto bufB (written by k_front, consumed by
    // k_F1; both complete before agg1 writes bufB) ----
    char* rb = (char*)bufB;
    size_t ro = 0;
    auto ralloc = [&](size_t bytes)->char*{
        ro = (ro + 255) & ~(size_t)255;
        char* p = rb + ro; ro += bytes; return p;
    };
    int* toff_g   = (int*)ralloc(NB*VG*4);
    int* toff_l   = (int*)ralloc(NB*VL*4);
    int* tcnt_g   = (int*)ralloc(NB*VG*4);
    int* tcnt_l   = (int*)ralloc(NB*VL*4);
    u16* bucket_g = (u16*)ralloc((size_t)NB*SG*2);
    u16* bucket_l = (u16*)ralloc((size_t)NB*SL*2);
    bf16* Wr1     = (bf16*)ralloc((size_t)SG*256*2);
    bf16* Wr2     = (bf16*)ralloc((size_t)SL*256*2);

    hipMemsetAsync(d_ws, 0, zero_bytes, stream);

    // ---- front: bucketing U buildG U edge_deg U transposeW U cast U bias0 --
    k_front<<<2*NB + NGB + EDB + SG + SL + CASTB + 32, 256, 0, stream>>>(
        rna_g, rna_l, tcnt_g, toff_g, bucket_g, tcnt_l, toff_l, bucket_l,
        convW1, convW2, Wr1, Wr2, fcxrW, convb1, convb2, bias0,
        e_dst, ew, packed, slot,
        emb1, emb2, G1, G2, pro_x, xb0);

    // ---- F1: buildA (bf16 Wr, L2-resident) + folded prep/out0-init ----
    k_F1<<<NA + 50, 256, 0, stream>>>(Wr1, Wr2,
                                      bucket_g, toff_g, tcnt_g, Ag,
                                      bucket_l, toff_l, tcnt_l, Al,
                                      packed, cnt, dis12, self12, pbatch, gstart,
                                      bsum, fcxrb, bias0, out0);
    k_scan3<<<49, 256, 0, stream>>>(cnt, bsum, offs);

    // ---- F2: edge scatter (split 8B records) ----
    k_F2<<<EDB, 256, 0, stream>>>(e_src, e_dst, ew, dis12, offs, slot, epA, epB);

    // ---- GCN layer 1 (33 -> 33), input stride 40 ----
    k_agg_gemm<5,8,80,0><<<AGB, 256, 0, stream>>>(xb0, epA, offs, cnt, self12,
                                                  g1W, g1b, bufB, bnpart1, 33, 33);
    k_bn_fin<<<1, 512, 0, stream>>>(bnpart1, bnsum1, 33);
    k_bn_apply<<<(NN*40+255)/256, 256, 0, stream>>>(bufB, bnsum1, bn1g, bn1b,
                                                    xbA, 33, 40, NN*40);

    // ---- GCN layer 2 (33 -> 66), input stride 40 (xbA), output stride 72 ----
    k_agg_gemm<5,8,80,1><<<AGB, 256, 0, stream>>>(xbA, epB, offs, cnt, self12,
                                                  g2W, g2b, bufB, bnpart2, 33, 66);
    k_bn_fin<<<1, 512, 0, stream>>>(bnpart2, bnsum2, 66);
    k_bn_apply<<<(NN*72+255)/256, 256, 0, stream>>>(bufB, bnsum2, bn2g, bn2b,
                                                    xbB, 66, 72, NN*72);

    // ---- GCN layer 3 (66 -> 132)  U  RNA-head gemmR ----
    k_L3<<<AGB + 1120, 256, 0, stream>>>(xbB, epB, offs, cnt, self12,
                                         g3W, g3b, bufB, bnpart3, Ag, G1, Al, G2, out0);
    k_bn_fin<<<1, 512, 0, stream>>>(bnpart3, bnsum3, 132);

    // ---- fused BN3-apply + pool + fcg1 + fcg2 ----
    k_fcgF<<<NG, 1024, 0, stream>>>(bufB, bnsum3, bn3g, bn3b, gstart,
                                    fcg1W, fcg1b, fcg2W, fcg2b, out1);
}

// Round 9
// 570.400 us; speedup vs baseline: 1.0423x; 1.0115x over previous
//
#include <hip/hip_runtime.h>
#include <hip/hip_bf16.h>

typedef __hip_bfloat16 bf16;
typedef unsigned short u16;

#define NN 50000      // nodes
#define NE 1600000    // edges (= 6250*256 exactly)
#define NG 128        // graphs
#define NB 128        // rna batch
#define SG 3000       // global seq (channels)
#define SL 2998       // local seq
#define VG 5          // global vocab
#define VL 65         // local vocab
#define EDB 6250      // edge blocks (NE/256)
#define AGB 12500     // agg blocks (NN/4)
#define NA  (NB*VG + NB*VL)   // 1490 buildA blocks
#define NGB (32*VG + 32*VL)   // 2240 buildG blocks
#define CASTB ((NN*40+255)/256)  // 7813

__device__ __forceinline__ float b2f(bf16 x){ return __bfloat162float(x); }
__device__ __forceinline__ float blo(unsigned u){ return __uint_as_float(u << 16); }
__device__ __forceinline__ float bhi(unsigned u){ return __uint_as_float(u & 0xffff0000u); }

// ---------------- buildG (runs inside k_front) -----------------------------
// G row index matches buildA's k' = v*256 + o*8 + k.
__device__ void dev_buildG(float (*rows)[128], const float* __restrict__ emb,
                           const float* __restrict__ W, bf16* __restrict__ G,
                           int V, int q){
    int o = q / V, mt = q - o*V;      // M = 8V, one block = 8 consecutive m
    int t = threadIdx.x;              // 256
    int j = t & 127, half = t >> 7;
    int kk[4], vv[4];
    #pragma unroll
    for (int qq = 0; qq < 4; ++qq){
        int mm = half*4 + qq;
        int m = mt*8 + mm;
        int k = m / V, v = m - k*V;
        kk[qq] = k; vv[qq] = v;
        rows[mm][j] = emb[v*128 + j];
    }
    __syncthreads();
    float a0=0.f, a1=0.f, a2=0.f, a3=0.f;
    const float* Wo = W + o*121*128 + j;
    for (int l = 0; l < 121; ++l){
        float w = Wo[l*128];
        a0 += rows[half*4+0][l + kk[0]] * w;
        a1 += rows[half*4+1][l + kk[1]] * w;
        a2 += rows[half*4+2][l + kk[2]] * w;
        a3 += rows[half*4+3][l + kk[3]] * w;
    }
    float a[4] = {a0, a1, a2, a3};
    #pragma unroll
    for (int qq = 0; qq < 4; ++qq){
        int row = vv[qq]*256 + o*8 + kk[qq];
        G[(size_t)row*128 + j] = __float2bfloat16(a[qq]);
    }
}

// ------- k_front: bucketing U buildG U edge_deg U transposeW U cast U bias0
__global__ void k_front(const int* __restrict__ rna_g, const int* __restrict__ rna_l,
                        int* __restrict__ tcnt_g, int* __restrict__ toff_g,
                        u16* __restrict__ bucket_g,
                        int* __restrict__ tcnt_l, int* __restrict__ toff_l,
                        u16* __restrict__ bucket_l,
                        const float* __restrict__ convW1, const float* __restrict__ convW2,
                        bf16* __restrict__ Wr1, bf16* __restrict__ Wr2,
                        const float* __restrict__ fcxrW, const float* __restrict__ cb1,
                        const float* __restrict__ cb2, float* __restrict__ bias0,
                        const int* __restrict__ dst, const float* __restrict__ ew,
                        double* __restrict__ packed, int* __restrict__ slot,
                        const float* __restrict__ emb1, const float* __restrict__ emb2,
                        bf16* __restrict__ G1, bf16* __restrict__ G2,
                        const float* __restrict__ pro_x, bf16* __restrict__ xb0){
    __shared__ int hist[VL], pre[VL], cur[VL];
    __shared__ float rows[8][128];
    int bx = blockIdx.x;
    int t = threadIdx.x;
    if (bx < 2*NB){
        int br = bx & 1, b = bx >> 1;
        const int* tok = br ? rna_l : rna_g;
        int S = br ? SL : SG, V = br ? VL : VG;
        int* tcnt = br ? tcnt_l : tcnt_g;
        int* toff = br ? toff_l : toff_g;
        u16* bucket = br ? bucket_l : bucket_g;
        if (t < V) hist[t] = 0;
        __syncthreads();
        for (int i = t; i < S; i += 256) atomicAdd(&hist[tok[b*S + i]], 1);
        __syncthreads();
        if (t == 0){
            int run = 0;
            for (int v = 0; v < V; ++v){ pre[v] = run; run += hist[v]; }
        }
        __syncthreads();
        if (t < V){
            tcnt[b*V + t] = hist[t];
            toff[b*V + t] = pre[t];
            cur[t] = pre[t];
        }
        __syncthreads();
        for (int i = t; i < S; i += 256){
            int v = tok[b*S + i];
            int p = atomicAdd(&cur[v], 1);
            bucket[b*S + p] = (u16)i;
        }
        return;
    }
    bx -= 2*NB;
    if (bx < NGB){
        if (bx < 32*VG) dev_buildG(rows, emb1, fcxrW, G1, VG, bx);
        else dev_buildG(rows, emb2, fcxrW, G2, VL, bx - 32*VG);
        return;
    }
    bx -= NGB;
    if (bx < EDB){
        int e = bx*256 + t;
        double old = unsafeAtomicAdd(&packed[dst[e]], 1048576.0 + (double)ew[e]);
        slot[e] = (int)(old * (1.0/1048576.0));
        return;
    }
    bx -= EDB;
    if (bx < SG + SL){
        const float* W; bf16* Wr; int S, c = bx;
        if (c < SG){ W = convW1; Wr = Wr1; S = SG; }
        else { c -= SG; W = convW2; Wr = Wr2; S = SL; }
        Wr[c*256 + t] = __float2bfloat16(W[((t >> 3)*S + c)*8 + (t & 7)]);
        return;
    }
    bx -= SG + SL;
    if (bx < CASTB){
        int i = bx*256 + t;           // cast pro_x -> padded bf16 [NN,40]
        if (i >= NN*40) return;
        int n = i / 40, f = i - n*40;
        xb0[i] = __float2bfloat16(f < 33 ? pro_x[n*33 + f] : 0.f);
        return;
    }
    bx -= CASTB;
    if (t >= 128) return;
    int o = bx, j = t;
    float s = 0.f;
    const float* Wo = fcxrW + o*121*128 + j;
    for (int l = 0; l < 121; ++l) s += Wo[l*128];
    unsafeAtomicAdd(&bias0[j], 0.5f * (cb1[o] + cb2[o]) * s);
}

// ---------------- buildA: K index k' = v*256 + t  (coalesced store) --------
// Wr is bf16 (3 MB table -> fits per-XCD L2); accumulate fp32.
// NOTE invariant: gemmR pairs X[b, k'] with G[k', j]. Both A and G use
// k' = v*256 + (o*8+k); gemmR's 256-wide kpart chunks == v partitions.
__device__ void dev_buildA(const bf16* __restrict__ Wr, const u16* __restrict__ bucket,
                           const int* __restrict__ toff, const int* __restrict__ tcnt,
                           float* __restrict__ A, int S, int V, int bv){
    int b = bv / V, v = bv - b*V;
    int t = threadIdx.x;            // t = o*8+k
    const u16* bk = bucket + b*S + toff[b*V + v];
    int m = tcnt[b*V + v];
    float acc = 0.f;
    int idx = 0;
    for (; idx + 4 <= m; idx += 4){
        int c0 = bk[idx], c1 = bk[idx+1], c2 = bk[idx+2], c3 = bk[idx+3];
        acc += b2f(Wr[c0*256 + t]);
        acc += b2f(Wr[c1*256 + t]);
        acc += b2f(Wr[c2*256 + t]);
        acc += b2f(Wr[c3*256 + t]);
    }
    for (; idx < m; ++idx) acc += b2f(Wr[bk[idx]*256 + t]);
    A[b*(256*V) + v*256 + t] = acc;   // contiguous in t: 1KB coalesced/block
}

// ---------------- k_prep: node prep + out0 init (50 blocks) ----------------
__global__ void k_prep(const double* __restrict__ packed, int* __restrict__ cnt,
                       float2* __restrict__ dis12, float2* __restrict__ self12,
                       const int* __restrict__ batch, int* __restrict__ gstart,
                       int* __restrict__ bsum,
                       const float* __restrict__ fcxrb, const float* __restrict__ bias0,
                       float* __restrict__ out0){
    __shared__ int sd[256];
    int t = threadIdx.x;
    if (blockIdx.x == 49){
        for (int idx = t; idx < NB*128; idx += 256)
            out0[idx] = fcxrb[idx & 127] + bias0[idx & 127];
        return;
    }
    int base = blockIdx.x*1024;
    int s = 0;
    #pragma unroll
    for (int j = 0; j < 4; ++j){
        int i = base + t*4 + j;
        if (i < NN){
            double p = packed[i];
            int c = (int)(p * (1.0/1048576.0));
            float w = (float)(p - (double)c * 1048576.0);
            cnt[i] = c; s += c;
            float r1 = rsqrtf(w + 1.0f);
            float r2 = rsqrtf((float)c + 1.0f);
            dis12[i] = make_float2(r1, r2);
            self12[i] = make_float2(r1*r1, r2*r2);
            int pb = batch[i];
            int prev = (i == 0) ? -1 : batch[i-1];
            for (int g = prev + 1; g <= pb; ++g) gstart[g] = i;
            if (i == NN - 1){
                for (int g = pb + 1; g <= NG; ++g) gstart[g] = NN;
            }
        }
    }
    sd[t] = s; __syncthreads();
    for (int d = 128; d > 0; d >>= 1){
        if (t < d) sd[t] += sd[t+d];
        __syncthreads();
    }
    if (t == 0) bsum[blockIdx.x] = sd[0];
}

// scan3 with inline cross-block prefix (bsum holds raw per-block sums)
__global__ void k_scan3(const int* __restrict__ cnt, const int* __restrict__ bsum,
                        int* __restrict__ offs){
    __shared__ int sd[256];
    __shared__ int sbase;
    int t = threadIdx.x;
    if (t == 0){
        int run = 0;
        for (int i = 0; i < blockIdx.x; ++i) run += bsum[i];
        sbase = run;
    }
    int base = blockIdx.x*1024;
    int loc[4]; int s = 0;
    #pragma unroll
    for (int j = 0; j < 4; ++j){
        int idx = base + t*4 + j;
        loc[j] = (idx < NN) ? cnt[idx] : 0;
        s += loc[j];
    }
    sd[t] = s; __syncthreads();
    for (int d = 1; d < 256; d <<= 1){
        int v = (t >= d) ? sd[t-d] : 0;
        __syncthreads();
        sd[t] += v;
        __syncthreads();
    }
    int run = sbase + (sd[t] - s);
    #pragma unroll
    for (int j = 0; j < 4; ++j){
        int idx = base + t*4 + j;
        if (idx < NN) offs[idx] = run;
        run += loc[j];
    }
}

// ---------------- F2: buildA (LPT-first) U edge scatter --------------------
// buildA depends only on k_front outputs (buckets, Wr) — independent of
// prep/scan3 — so its L2-resident streaming overlaps the scatter's
// write-stream (which needs no L2 retention; no r4-style thrash).
// epA record: {src index (int bits), norm layer 1}; epB: {src, norm layers 2/3}
__global__ void k_F2(const bf16* __restrict__ Wr1, const bf16* __restrict__ Wr2,
                     const u16* __restrict__ bucket_g, const int* __restrict__ toff_g,
                     const int* __restrict__ tcnt_g, float* __restrict__ Ag,
                     const u16* __restrict__ bucket_l, const int* __restrict__ toff_l,
                     const int* __restrict__ tcnt_l, float* __restrict__ Al,
                     const int* __restrict__ src, const int* __restrict__ dst,
                     const float* __restrict__ ew, const float2* __restrict__ dis12,
                     const int* __restrict__ offs, const int* __restrict__ slot,
                     float2* __restrict__ epA, float2* __restrict__ epB){
    int bx = blockIdx.x;
    if (bx < NA){
        if (bx < NB*VG) dev_buildA(Wr1, bucket_g, toff_g, tcnt_g, Ag, SG, VG, bx);
        else dev_buildA(Wr2, bucket_l, toff_l, tcnt_l, Al, SL, VL, bx - NB*VG);
        return;
    }
    int e = (bx - NA)*256 + threadIdx.x;
    int s = src[e], d = dst[e];
    int pos = offs[d] + slot[e];
    float2 a = dis12[s], b = dis12[d];
    epA[pos] = make_float2(__int_as_float(s), a.x * ew[e] * b.x);
    epB[pos] = make_float2(__int_as_float(s), a.y * b.y);
}

// ---------------- fused aggregate + GEMM (uint4 rows) ----------------
// Round-2 loop body (frozen — best of lane-util/prefetch/stripe variants).
// Edge records are 8B {src, norm}; byte offsets reconstructed as src*STRIDE.
// Predicated parallel tail. BN partial stats fused (64-way strided atomics).
template<int QV, int GRP, int STRIDE, int SZ>
__device__ void dev_agg(float* sAgg /* [4][QV*8] */,
                        const bf16* __restrict__ xb, const float2* __restrict__ ep,
                        const int* __restrict__ offs, const int* __restrict__ cnt,
                        const float2* __restrict__ self12,
                        const float* __restrict__ W, const float* __restrict__ bias,
                        float* __restrict__ tout, float* __restrict__ bnpart,
                        int F, int OF, int bx){
    const int LPG = 64 / GRP;
    int wave = threadIdx.x >> 6;
    int node = bx*4 + wave;
    int lane = threadIdx.x & 63;
    int grp  = lane / LPG;
    int gl   = lane % LPG;
    bool act = gl < QV;
    const char* xc = (const char*)xb;
    float a0=0,a1=0,a2=0,a3=0,a4=0,a5=0,a6=0,a7=0;
    int b = offs[node], e = b + cnt[node];
    if (act){
        int fo = gl << 4;   // lane byte offset within row
        if (grp == 0){
            float2 sw2 = self12[node];
            float sw = SZ ? sw2.y : sw2.x;
            uint4 u = *(const uint4*)(xc + node*(QV*16) + fo);
            a0 = sw*blo(u.x); a1 = sw*bhi(u.x); a2 = sw*blo(u.y); a3 = sw*bhi(u.y);
            a4 = sw*blo(u.z); a5 = sw*bhi(u.z); a6 = sw*blo(u.w); a7 = sw*bhi(u.w);
        }
        int p = b + grp;
        for (; p + 3*GRP < e; p += 4*GRP){
            float2 e0 = ep[p];
            float2 e1 = ep[p +   GRP];
            float2 e2 = ep[p + 2*GRP];
            float2 e3 = ep[p + 3*GRP];
            int o0 = __float_as_int(e0.x)*STRIDE; float n0 = e0.y;
            int o1 = __float_as_int(e1.x)*STRIDE; float n1 = e1.y;
            int o2 = __float_as_int(e2.x)*STRIDE; float n2 = e2.y;
            int o3 = __float_as_int(e3.x)*STRIDE; float n3 = e3.y;
            uint4 u0 = *(const uint4*)(xc + o0 + fo);
            uint4 u1 = *(const uint4*)(xc + o1 + fo);
            uint4 u2 = *(const uint4*)(xc + o2 + fo);
            uint4 u3 = *(const uint4*)(xc + o3 + fo);
            a0 += n0*blo(u0.x); a1 += n0*bhi(u0.x); a2 += n0*blo(u0.y); a3 += n0*bhi(u0.y);
            a4 += n0*blo(u0.z); a5 += n0*bhi(u0.z); a6 += n0*blo(u0.w); a7 += n0*bhi(u0.w);
            a0 += n1*blo(u1.x); a1 += n1*bhi(u1.x); a2 += n1*blo(u1.y); a3 += n1*bhi(u1.y);
            a4 += n1*blo(u1.z); a5 += n1*bhi(u1.z); a6 += n1*blo(u1.w); a7 += n1*bhi(u1.w);
            a0 += n2*blo(u2.x); a1 += n2*bhi(u2.x); a2 += n2*blo(u2.y); a3 += n2*bhi(u2.y);
            a4 += n2*blo(u2.z); a5 += n2*bhi(u2.z); a6 += n2*blo(u2.w); a7 += n2*bhi(u2.w);
            a0 += n3*blo(u3.x); a1 += n3*bhi(u3.x); a2 += n3*blo(u3.y); a3 += n3*bhi(u3.y);
            a4 += n3*blo(u3.z); a5 += n3*bhi(u3.z); a6 += n3*blo(u3.w); a7 += n3*bhi(u3.w);
        }
        if (p < e){   // predicated tail, <= 3 edges per group
            int p1 = p + GRP, p2 = p + 2*GRP;
            bool v1 = p1 < e, v2 = p2 < e;
            float2 e0 = ep[p];
            float2 e1 = ep[v1 ? p1 : p];
            float2 e2 = ep[v2 ? p2 : p];
            int o0 = __float_as_int(e0.x)*STRIDE;
            int o1 = __float_as_int(e1.x)*STRIDE;
            int o2 = __float_as_int(e2.x)*STRIDE;
            float n0 = e0.y;
            float n1 = v1 ? e1.y : 0.f;
            float n2 = v2 ? e2.y : 0.f;
            uint4 u0 = *(const uint4*)(xc + o0 + fo);
            uint4 u1 = *(const uint4*)(xc + o1 + fo);
            uint4 u2 = *(const uint4*)(xc + o2 + fo);
            a0 += n0*blo(u0.x); a1 += n0*bhi(u0.x); a2 += n0*blo(u0.y); a3 += n0*bhi(u0.y);
            a4 += n0*blo(u0.z); a5 += n0*bhi(u0.z); a6 += n0*blo(u0.w); a7 += n0*bhi(u0.w);
            a0 += n1*blo(u1.x); a1 += n1*bhi(u1.x); a2 += n1*blo(u1.y); a3 += n1*bhi(u1.y);
            a4 += n1*blo(u1.z); a5 += n1*bhi(u1.z); a6 += n1*blo(u1.w); a7 += n1*bhi(u1.w);
            a0 += n2*blo(u2.x); a1 += n2*bhi(u2.x); a2 += n2*blo(u2.y); a3 += n2*bhi(u2.y);
            a4 += n2*blo(u2.z); a5 += n2*bhi(u2.z); a6 += n2*blo(u2.w); a7 += n2*bhi(u2.w);
        }
    }
    #pragma unroll
    for (int m = LPG; m < 64; m <<= 1){
        a0 += __shfl_xor(a0, m); a1 += __shfl_xor(a1, m);
        a2 += __shfl_xor(a2, m); a3 += __shfl_xor(a3, m);
        a4 += __shfl_xor(a4, m); a5 += __shfl_xor(a5, m);
        a6 += __shfl_xor(a6, m); a7 += __shfl_xor(a7, m);
    }
    if (act && grp == 0){
        float4* dst = (float4*)&sAgg[wave*(QV*8) + gl*8];
        dst[0] = make_float4(a0, a1, a2, a3);
        dst[1] = make_float4(a4, a5, a6, a7);
    }
    __syncthreads();
    int i0 = bx*4;
    int j = threadIdx.x;
    if (j < OF){
        float c0 = bias[j], c1 = c0, c2 = c0, c3 = c0;
        const float* Wj = W + j;
        const float* s0 = sAgg;
        const float* s1 = sAgg + QV*8;
        const float* s2 = sAgg + 2*QV*8;
        const float* s3 = sAgg + 3*QV*8;
        #pragma unroll 4
        for (int f = 0; f < F; ++f){
            float w = Wj[f*OF];
            c0 += s0[f]*w; c1 += s1[f]*w; c2 += s2[f]*w; c3 += s3[f]*w;
        }
        tout[(size_t)(i0+0)*OF + j] = c0;
        tout[(size_t)(i0+1)*OF + j] = c1;
        tout[(size_t)(i0+2)*OF + j] = c2;
        tout[(size_t)(i0+3)*OF + j] = c3;
        // fused BN partial stats (64-way strided to dodge contention)
        float s  = c0 + c1 + c2 + c3;
        float ss = c0*c0 + c1*c1 + c2*c2 + c3*c3;
        float* part = bnpart + (bx & 63)*(2*OF);
        unsafeAtomicAdd(&part[j], s);
        unsafeAtomicAdd(&part[OF + j], ss);
    }
}

template<int QV, int GRP, int STRIDE, int SZ>
__global__ __launch_bounds__(256, 8)
void k_agg_gemm(const bf16* __restrict__ xb, const float2* __restrict__ ep,
                const int* __restrict__ offs, const int* __restrict__ cnt,
                const float2* __restrict__ self12,
                const float* __restrict__ W, const float* __restrict__ bias,
                float* __restrict__ tout, float* __restrict__ bnpart,
                int F, int OF){
    __shared__ float sAgg[4*QV*8];
    dev_agg<QV,GRP,STRIDE,SZ>(sAgg, xb, ep, offs, cnt, self12, W, bias,
                              tout, bnpart, F, OF, blockIdx.x);
}

// gemmR for 256 threads: 8 b-rows x 256-K slice, atomic epilogue
__device__ void dev_gemmR(float* xs /* [8][256] */, int bq,
                          const float* __restrict__ Ag, const bf16* __restrict__ G1,
                          const float* __restrict__ Al, const bf16* __restrict__ G2,
                          float* __restrict__ out0){
    int kpart = bq >> 4;       // 0..69
    int bgrp  = bq & 15;
    const float* X; const bf16* G; int K, k0;
    if (kpart < 5){ X = Ag; G = G1; K = 1280;  k0 = kpart*256; }
    else          { X = Al; G = G2; K = 16640; k0 = (kpart-5)*256; }
    int b0 = bgrp*8;
    int t = threadIdx.x;
    #pragma unroll
    for (int i = 0; i < 8; ++i)
        xs[i*256 + t] = X[(b0+i)*K + k0 + t];
    __syncthreads();
    int rq = t >> 7, j = t & 127;
    const float* x0 = xs + (rq*4)*256;
    float a0=0,a1=0,a2=0,a3=0;
    const bf16* Gp = G + (size_t)k0*128 + j;
    for (int kk = 0; kk < 256; ++kk){
        float g = b2f(Gp[kk*128]);
        a0 += x0[kk]*g; a1 += x0[256+kk]*g; a2 += x0[512+kk]*g; a3 += x0[768+kk]*g;
    }
    unsafeAtomicAdd(&out0[(b0+rq*4+0)*128 + j], 0.5f*a0);
    unsafeAtomicAdd(&out0[(b0+rq*4+1)*128 + j], 0.5f*a1);
    unsafeAtomicAdd(&out0[(b0+rq*4+2)*128 + j], 0.5f*a2);
    unsafeAtomicAdd(&out0[(b0+rq*4+3)*128 + j], 0.5f*a3);
}

// L3 aggregate+gemm  U  gemmR (RNA head backfills L3's latency stalls)
__global__ void k_L3(const bf16* __restrict__ xb, const float2* __restrict__ ep,
                     const int* __restrict__ offs, const int* __restrict__ cnt,
                     const float2* __restrict__ self12,
                     const float* __restrict__ W, const float* __restrict__ bias,
                     float* __restrict__ tout, float* __restrict__ bnpart,
                     const float* __restrict__ Ag, const bf16* __restrict__ G1,
                     const float* __restrict__ Al, const bf16* __restrict__ G2,
                     float* __restrict__ out0){
    __shared__ float smem[8*256];
    int bx = blockIdx.x;
    if (bx < AGB){
        dev_agg<9,4,144,1>(smem, xb, ep, offs, cnt, self12, W, bias, tout, bnpart,
                           66, 132, bx);
    } else {
        dev_gemmR(smem, bx - AGB, Ag, G1, Al, G2, out0);
    }
}

// reduce 64-way strided BN partials -> sums (1 block)
__global__ void k_bn_fin(const float* __restrict__ part, float* __restrict__ sums, int OF){
    int tid = threadIdx.x;
    if (tid >= 2*OF) return;
    float s = 0.f;
    #pragma unroll 8
    for (int k = 0; k < 64; ++k) s += part[k*(2*OF) + tid];
    sums[tid] = s;
}

// fused finalize+apply, flattened; padded bf16 out (stride OS)
__global__ void k_bn_apply(const float* __restrict__ t, const float* __restrict__ sums,
                           const float* __restrict__ g, const float* __restrict__ b,
                           bf16* __restrict__ xo, int OF, int OS, int total){
    int id = blockIdx.x*256 + threadIdx.x;
    if (id >= total) return;
    int i = id / OS, f = id - i*OS;
    float v = 0.f;
    if (f < OF){
        float m  = sums[f] * (1.0f/(float)NN);
        float vr = sums[OF + f] * (1.0f/(float)NN) - m*m;
        float sc = g[f] * rsqrtf(vr + 1e-5f);
        float sh = b[f] - m*sc;
        v = t[(size_t)i*OF + f] * sc + sh;
        v = v > 0.f ? v : 0.f;
    }
    xo[id] = __float2bfloat16(v);
}

// fused BN3-apply + pool + fcg1 + fcg2: block g does everything for graph g
// (reads finalized bnsum3 -> no extra atomic contention)
__global__ void k_fcgF(const float* __restrict__ bufB, const float* __restrict__ sums,
                       const float* __restrict__ bn3g, const float* __restrict__ bn3b,
                       const int* __restrict__ gstart,
                       const float* __restrict__ W1, const float* __restrict__ b1,
                       const float* __restrict__ W2, const float* __restrict__ b2,
                       float* __restrict__ out){
    __shared__ float scs[132], shs[132];
    __shared__ float pp[7][132];
    __shared__ float pr[132];
    __shared__ float hr[1024];
    __shared__ float part[8][128];
    int g = blockIdx.x, t = threadIdx.x;   // 1024
    if (t < 132){
        float m  = sums[t] * (1.0f/(float)NN);
        float vr = sums[132 + t] * (1.0f/(float)NN) - m*m;
        float sc = bn3g[t] * rsqrtf(vr + 1e-5f);
        scs[t] = sc;
        shs[t] = bn3b[t] - m*sc;
    }
    __syncthreads();
    int i0 = gstart[g], i1 = gstart[g+1];
    int r = t / 132, f = t - r*132;
    if (r < 7){
        float acc = 0.f;
        for (int i = i0 + r; i < i1; i += 7){
            float v = bufB[(size_t)i*132 + f] * scs[f] + shs[f];
            acc += v > 0.f ? v : 0.f;
        }
        pp[r][f] = acc;
    }
    __syncthreads();
    if (t < 132){
        float s = 0.f;
        #pragma unroll
        for (int k = 0; k < 7; ++k) s += pp[k][t];
        float inv = 1.0f / fmaxf((float)(i1 - i0), 1.0f);
        pr[t] = s * inv;
    }
    __syncthreads();
    float acc = b1[t];
    #pragma unroll 4
    for (int ff = 0; ff < 132; ++ff) acc += pr[ff] * W1[ff*1024 + t];
    hr[t] = acc > 0.f ? acc : 0.f;
    __syncthreads();
    int ks = t >> 7, j = t & 127;
    const float* Wp = W2 + (ks*128)*128 + j;
    const float* hp = hr + ks*128;
    float a = 0.f;
    #pragma unroll 8
    for (int kk = 0; kk < 128; ++kk) a += hp[kk] * Wp[(size_t)kk*128];
    part[ks][j] = a;
    __syncthreads();
    if (t < 128){
        float s = b2[t];
        #pragma unroll
        for (int rr = 0; rr < 8; ++rr) s += part[rr][t];
        out[g*128 + t] = s;
    }
}

extern "C" void kernel_launch(void* const* d_in, const int* in_sizes, int n_in,
                              void* d_out, int out_size, void* d_ws, size_t ws_size,
                              hipStream_t stream)
{
    (void)in_sizes; (void)n_in; (void)out_size; (void)ws_size;

    const float* pro_x  = (const float*)d_in[0];
    const int*   eidx   = (const int*)  d_in[1];
    const float* ew     = (const float*)d_in[2];
    const int*   pbatch = (const int*)  d_in[3];
    const int*   rna_g  = (const int*)  d_in[4];
    const int*   rna_l  = (const int*)  d_in[5];
    const float* emb1   = (const float*)d_in[6];
    const float* emb2   = (const float*)d_in[7];
    const float* convW1 = (const float*)d_in[8];
    const float* convb1 = (const float*)d_in[9];
    const float* convW2 = (const float*)d_in[10];
    const float* convb2 = (const float*)d_in[11];
    const float* fcxrW  = (const float*)d_in[12];
    const float* fcxrb  = (const float*)d_in[13];
    const float* g1W = (const float*)d_in[14];
    const float* g1b = (const float*)d_in[15];
    const float* g2W = (const float*)d_in[16];
    const float* g2b = (const float*)d_in[17];
    const float* g3W = (const float*)d_in[18];
    const float* g3b = (const float*)d_in[19];
    const float* bn1g = (const float*)d_in[20];
    const float* bn1b = (const float*)d_in[21];
    const float* bn2g = (const float*)d_in[22];
    const float* bn2b = (const float*)d_in[23];
    const float* bn3g = (const float*)d_in[24];
    const float* bn3b = (const float*)d_in[25];
    const float* fcg1W = (const float*)d_in[26];
    const float* fcg1b = (const float*)d_in[27];
    const float* fcg2W = (const float*)d_in[28];
    const float* fcg2b = (const float*)d_in[29];

    const int* e_src = eidx;
    const int* e_dst = eidx + NE;

    char* base = (char*)d_ws;
    size_t off = 0;
    auto alloc = [&](size_t bytes)->char*{
        off = (off + 255) & ~(size_t)255;
        char* p = base + off; off += bytes; return p;
    };

    // ---- zero zone (single memset) ----
    double* packed  = (double*)alloc(NN*8);
    float* bnsum1  = (float*)alloc(2*33*4);
    float* bnsum2  = (float*)alloc(2*66*4);
    float* bnsum3  = (float*)alloc(2*132*4);
    float* bias0   = (float*)alloc(128*4);
    float* bnpart1 = (float*)alloc(64*2*33*4);
    float* bnpart2 = (float*)alloc(64*2*66*4);
    float* bnpart3 = (float*)alloc(64*2*132*4);
    size_t zero_bytes = (off + 255) & ~(size_t)255;

    // ---- persistent buffers ----
    int*    cnt    = (int*)   alloc(NN*4);
    float2* dis12  = (float2*)alloc(NN*8);
    float2* self12 = (float2*)alloc(NN*8);
    int*    offs   = (int*)   alloc(NN*4);
    int*    bsum   = (int*)   alloc(64*4);
    int*    gstart = (int*)   alloc((NG+1)*4);
    float2* epA    = (float2*)alloc((size_t)NE*8);
    float2* epB    = (float2*)alloc((size_t)NE*8);
    float*  bufB   = (float*) alloc((size_t)NN*132*4);   // t (max OF=132)
    bf16*   xbA    = (bf16*)  alloc((size_t)NE*4);       // >= max(slot 6.4MB, NN*40*2)
    bf16*   xbB    = (bf16*)  alloc((size_t)NN*72*2);    // stride-72 features
    float*  Ag     = (float*) alloc((size_t)NB*256*VG*4);   // persistent: read by k_L3
    float*  Al     = (float*) alloc((size_t)NB*256*VL*4);
    bf16*   G1     = (bf16*)  alloc((size_t)32*8*VG*128*2);
    bf16*   G2     = (bf16*)  alloc((size_t)32*8*VL*128*2);

    // slot aliases xbA (consumed by F2 scatter before L1 bn_apply writes xbA)
    int*  slot = (int*)xbA;
    // xb0 (stride-40 cast, 4MB) aliases xbB: front cast -> agg1 reads xb0 ->
    // bn_apply2 overwrites xbB. Safe.
    bf16* xb0  = (bf16*)xbB;

    float* out0 = (float*)d_out;          // xc_rna
    float* out1 = (float*)d_out + 16384;  // xp_out

    // ---- RNA scratch aliased onto bufB (written by k_front, consumed by
    // k_F2 buildA; both complete before agg1 writes bufB) ----
    char* rb = (char*)bufB;
    size_t ro = 0;
    auto ralloc = [&](size_t bytes)->char*{
        ro = (ro + 255) & ~(size_t)255;
        char* p = rb + ro; ro += bytes; return p;
    };
    int* toff_g   = (int*)ralloc(NB*VG*4);
    int* toff_l   = (int*)ralloc(NB*VL*4);
    int* tcnt_g   = (int*)ralloc(NB*VG*4);
    int* tcnt_l   = (int*)ralloc(NB*VL*4);
    u16* bucket_g = (u16*)ralloc((size_t)NB*SG*2);
    u16* bucket_l = (u16*)ralloc((size_t)NB*SL*2);
    bf16* Wr1     = (bf16*)ralloc((size_t)SG*256*2);
    bf16* Wr2     = (bf16*)ralloc((size_t)SL*256*2);

    hipMemsetAsync(d_ws, 0, zero_bytes, stream);

    // ---- front: bucketing U buildG U edge_deg U transposeW U cast U bias0 --
    k_front<<<2*NB + NGB + EDB + SG + SL + CASTB + 32, 256, 0, stream>>>(
        rna_g, rna_l, tcnt_g, toff_g, bucket_g, tcnt_l, toff_l, bucket_l,
        convW1, convW2, Wr1, Wr2, fcxrW, convb1, convb2, bias0,
        e_dst, ew, packed, slot,
        emb1, emb2, G1, G2, pro_x, xb0);

    // ---- prep (50 blocks) + scan ----
    k_prep<<<50, 256, 0, stream>>>(packed, cnt, dis12, self12, pbatch, gstart,
                                   bsum, fcxrb, bias0, out0);
    k_scan3<<<49, 256, 0, stream>>>(cnt, bsum, offs);

    // ---- F2: buildA (LPT-first, L2-resident Wr) U edge scatter ----
    k_F2<<<NA + EDB, 256, 0, stream>>>(Wr1, Wr2,
                                       bucket_g, toff_g, tcnt_g, Ag,
                                       bucket_l, toff_l, tcnt_l, Al,
                                       e_src, e_dst, ew, dis12, offs, slot,
                                       epA, epB);

    // ---- GCN layer 1 (33 -> 33), input stride 40 ----
    k_agg_gemm<5,8,80,0><<<AGB, 256, 0, stream>>>(xb0, epA, offs, cnt, self12,
                                                  g1W, g1b, bufB, bnpart1, 33, 33);
    k_bn_fin<<<1, 512, 0, stream>>>(bnpart1, bnsum1, 33);
    k_bn_apply<<<(NN*40+255)/256, 256, 0, stream>>>(bufB, bnsum1, bn1g, bn1b,
                                                    xbA, 33, 40, NN*40);

    // ---- GCN layer 2 (33 -> 66), input stride 40 (xbA), output stride 72 ----
    k_agg_gemm<5,8,80,1><<<AGB, 256, 0, stream>>>(xbA, epB, offs, cnt, self12,
                                                  g2W, g2b, bufB, bnpart2, 33, 66);
    k_bn_fin<<<1, 512, 0, stream>>>(bnpart2, bnsum2, 66);
    k_bn_apply<<<(NN*72+255)/256, 256, 0, stream>>>(bufB, bnsum2, bn2g, bn2b,
                                                    xbB, 66, 72, NN*72);

    // ---- GCN layer 3 (66 -> 132)  U  RNA-head gemmR ----
    k_L3<<<AGB + 1120, 256, 0, stream>>>(xbB, epB, offs, cnt, self12,
                                         g3W, g3b, bufB, bnpart3, Ag, G1, Al, G2, out0);
    k_bn_fin<<<1, 512, 0, stream>>>(bnpart3, bnsum3, 132);

    // ---- fused BN3-apply + pool + fcg1 + fcg2 ----
    k_fcgF<<<NG, 1024, 0, stream>>>(bufB, bnsum3, bn3g, bn3b, gstart,
                                    fcg1W, fcg1b, fcg2W, fcg2b, out1);
}

// Round 10
// 567.721 us; speedup vs baseline: 1.0472x; 1.0047x over previous
//
#include <hip/hip_runtime.h>
#include <hip/hip_bf16.h>

typedef __hip_bfloat16 bf16;
typedef unsigned short u16;

#define NN 50000      // nodes
#define NE 1600000    // edges (= 6250*256 exactly)
#define NG 128        // graphs
#define NB 128        // rna batch
#define SG 3000       // global seq (channels)
#define SL 2998       // local seq
#define VG 5          // global vocab
#define VL 65         // local vocab
#define EDB 6250      // edge blocks (NE/256)
#define AGB 12500     // agg blocks (NN/4)
#define NA  (NB*VG + NB*VL)   // 1490 buildA blocks
#define NGB (32*VG + 32*VL)   // 2240 buildG blocks
#define CASTB ((NN*40+255)/256)  // 7813

__device__ __forceinline__ float b2f(bf16 x){ return __bfloat162float(x); }
__device__ __forceinline__ float blo(unsigned u){ return __uint_as_float(u << 16); }
__device__ __forceinline__ float bhi(unsigned u){ return __uint_as_float(u & 0xffff0000u); }

// ---------------- buildG (runs inside k_front) -----------------------------
// G row index matches buildA's k' = v*256 + o*8 + k.
__device__ void dev_buildG(float (*rows)[128], const float* __restrict__ emb,
                           const float* __restrict__ W, bf16* __restrict__ G,
                           int V, int q){
    int o = q / V, mt = q - o*V;      // M = 8V, one block = 8 consecutive m
    int t = threadIdx.x;              // 256
    int j = t & 127, half = t >> 7;
    int kk[4], vv[4];
    #pragma unroll
    for (int qq = 0; qq < 4; ++qq){
        int mm = half*4 + qq;
        int m = mt*8 + mm;
        int k = m / V, v = m - k*V;
        kk[qq] = k; vv[qq] = v;
        rows[mm][j] = emb[v*128 + j];
    }
    __syncthreads();
    float a0=0.f, a1=0.f, a2=0.f, a3=0.f;
    const float* Wo = W + o*121*128 + j;
    for (int l = 0; l < 121; ++l){
        float w = Wo[l*128];
        a0 += rows[half*4+0][l + kk[0]] * w;
        a1 += rows[half*4+1][l + kk[1]] * w;
        a2 += rows[half*4+2][l + kk[2]] * w;
        a3 += rows[half*4+3][l + kk[3]] * w;
    }
    float a[4] = {a0, a1, a2, a3};
    #pragma unroll
    for (int qq = 0; qq < 4; ++qq){
        int row = vv[qq]*256 + o*8 + kk[qq];
        G[(size_t)row*128 + j] = __float2bfloat16(a[qq]);
    }
}

// ------- k_front: bucketing U buildG U edge_deg U transposeW U cast U bias0
__global__ void k_front(const int* __restrict__ rna_g, const int* __restrict__ rna_l,
                        int* __restrict__ tcnt_g, int* __restrict__ toff_g,
                        u16* __restrict__ bucket_g,
                        int* __restrict__ tcnt_l, int* __restrict__ toff_l,
                        u16* __restrict__ bucket_l,
                        const float* __restrict__ convW1, const float* __restrict__ convW2,
                        bf16* __restrict__ Wr1, bf16* __restrict__ Wr2,
                        const float* __restrict__ fcxrW, const float* __restrict__ cb1,
                        const float* __restrict__ cb2, float* __restrict__ bias0,
                        const int* __restrict__ dst, const float* __restrict__ ew,
                        double* __restrict__ packed, int* __restrict__ slot,
                        const float* __restrict__ emb1, const float* __restrict__ emb2,
                        bf16* __restrict__ G1, bf16* __restrict__ G2,
                        const float* __restrict__ pro_x, bf16* __restrict__ xb0){
    __shared__ int hist[VL], pre[VL], cur[VL];
    __shared__ float rows[8][128];
    int bx = blockIdx.x;
    int t = threadIdx.x;
    if (bx < 2*NB){
        int br = bx & 1, b = bx >> 1;
        const int* tok = br ? rna_l : rna_g;
        int S = br ? SL : SG, V = br ? VL : VG;
        int* tcnt = br ? tcnt_l : tcnt_g;
        int* toff = br ? toff_l : toff_g;
        u16* bucket = br ? bucket_l : bucket_g;
        if (t < V) hist[t] = 0;
        __syncthreads();
        for (int i = t; i < S; i += 256) atomicAdd(&hist[tok[b*S + i]], 1);
        __syncthreads();
        if (t == 0){
            int run = 0;
            for (int v = 0; v < V; ++v){ pre[v] = run; run += hist[v]; }
        }
        __syncthreads();
        if (t < V){
            tcnt[b*V + t] = hist[t];
            toff[b*V + t] = pre[t];
            cur[t] = pre[t];
        }
        __syncthreads();
        for (int i = t; i < S; i += 256){
            int v = tok[b*S + i];
            int p = atomicAdd(&cur[v], 1);
            bucket[b*S + p] = (u16)i;
        }
        return;
    }
    bx -= 2*NB;
    if (bx < NGB){
        if (bx < 32*VG) dev_buildG(rows, emb1, fcxrW, G1, VG, bx);
        else dev_buildG(rows, emb2, fcxrW, G2, VL, bx - 32*VG);
        return;
    }
    bx -= NGB;
    if (bx < EDB){
        int e = bx*256 + t;
        double old = unsafeAtomicAdd(&packed[dst[e]], 1048576.0 + (double)ew[e]);
        slot[e] = (int)(old * (1.0/1048576.0));
        return;
    }
    bx -= EDB;
    if (bx < SG + SL){
        const float* W; bf16* Wr; int S, c = bx;
        if (c < SG){ W = convW1; Wr = Wr1; S = SG; }
        else { c -= SG; W = convW2; Wr = Wr2; S = SL; }
        Wr[c*256 + t] = __float2bfloat16(W[((t >> 3)*S + c)*8 + (t & 7)]);
        return;
    }
    bx -= SG + SL;
    if (bx < CASTB){
        int i = bx*256 + t;           // cast pro_x -> padded bf16 [NN,40]
        if (i >= NN*40) return;
        int n = i / 40, f = i - n*40;
        xb0[i] = __float2bfloat16(f < 33 ? pro_x[n*33 + f] : 0.f);
        return;
    }
    bx -= CASTB;
    if (t >= 128) return;
    int o = bx, j = t;
    float s = 0.f;
    const float* Wo = fcxrW + o*121*128 + j;
    for (int l = 0; l < 121; ++l) s += Wo[l*128];
    unsafeAtomicAdd(&bias0[j], 0.5f * (cb1[o] + cb2[o]) * s);
}

// ---------------- buildA: K index k' = v*256 + t  (coalesced store) --------
// Wr is bf16 (3 MB table -> fits per-XCD L2); accumulate fp32.
// NOTE invariant: gemmR pairs X[b, k'] with G[k', j]. Both A and G use
// k' = v*256 + (o*8+k); gemmR's 256-wide kpart chunks == v partitions.
__device__ void dev_buildA(const bf16* __restrict__ Wr, const u16* __restrict__ bucket,
                           const int* __restrict__ toff, const int* __restrict__ tcnt,
                           float* __restrict__ A, int S, int V, int bv){
    int b = bv / V, v = bv - b*V;
    int t = threadIdx.x;            // t = o*8+k
    const u16* bk = bucket + b*S + toff[b*V + v];
    int m = tcnt[b*V + v];
    float acc = 0.f;
    int idx = 0;
    for (; idx + 4 <= m; idx += 4){
        int c0 = bk[idx], c1 = bk[idx+1], c2 = bk[idx+2], c3 = bk[idx+3];
        acc += b2f(Wr[c0*256 + t]);
        acc += b2f(Wr[c1*256 + t]);
        acc += b2f(Wr[c2*256 + t]);
        acc += b2f(Wr[c3*256 + t]);
    }
    for (; idx < m; ++idx) acc += b2f(Wr[bk[idx]*256 + t]);
    A[b*(256*V) + v*256 + t] = acc;   // contiguous in t: 1KB coalesced/block
}

// ---------------- k_prep: node prep + out0 init (50 blocks) ----------------
__global__ void k_prep(const double* __restrict__ packed, int* __restrict__ cnt,
                       float2* __restrict__ dis12, float2* __restrict__ self12,
                       const int* __restrict__ batch, int* __restrict__ gstart,
                       int* __restrict__ bsum,
                       const float* __restrict__ fcxrb, const float* __restrict__ bias0,
                       float* __restrict__ out0){
    __shared__ int sd[256];
    int t = threadIdx.x;
    if (blockIdx.x == 49){
        for (int idx = t; idx < NB*128; idx += 256)
            out0[idx] = fcxrb[idx & 127] + bias0[idx & 127];
        return;
    }
    int base = blockIdx.x*1024;
    int s = 0;
    #pragma unroll
    for (int j = 0; j < 4; ++j){
        int i = base + t*4 + j;
        if (i < NN){
            double p = packed[i];
            int c = (int)(p * (1.0/1048576.0));
            float w = (float)(p - (double)c * 1048576.0);
            cnt[i] = c; s += c;
            float r1 = rsqrtf(w + 1.0f);
            float r2 = rsqrtf((float)c + 1.0f);
            dis12[i] = make_float2(r1, r2);
            self12[i] = make_float2(r1*r1, r2*r2);
            int pb = batch[i];
            int prev = (i == 0) ? -1 : batch[i-1];
            for (int g = prev + 1; g <= pb; ++g) gstart[g] = i;
            if (i == NN - 1){
                for (int g = pb + 1; g <= NG; ++g) gstart[g] = NN;
            }
        }
    }
    sd[t] = s; __syncthreads();
    for (int d = 128; d > 0; d >>= 1){
        if (t < d) sd[t] += sd[t+d];
        __syncthreads();
    }
    if (t == 0) bsum[blockIdx.x] = sd[0];
}

// scan3 with inline cross-block prefix (bsum holds raw per-block sums)
__global__ void k_scan3(const int* __restrict__ cnt, const int* __restrict__ bsum,
                        int* __restrict__ offs){
    __shared__ int sd[256];
    __shared__ int sbase;
    int t = threadIdx.x;
    if (t == 0){
        int run = 0;
        for (int i = 0; i < blockIdx.x; ++i) run += bsum[i];
        sbase = run;
    }
    int base = blockIdx.x*1024;
    int loc[4]; int s = 0;
    #pragma unroll
    for (int j = 0; j < 4; ++j){
        int idx = base + t*4 + j;
        loc[j] = (idx < NN) ? cnt[idx] : 0;
        s += loc[j];
    }
    sd[t] = s; __syncthreads();
    for (int d = 1; d < 256; d <<= 1){
        int v = (t >= d) ? sd[t-d] : 0;
        __syncthreads();
        sd[t] += v;
        __syncthreads();
    }
    int run = sbase + (sd[t] - s);
    #pragma unroll
    for (int j = 0; j < 4; ++j){
        int idx = base + t*4 + j;
        if (idx < NN) offs[idx] = run;
        run += loc[j];
    }
}

// ---------------- F2: buildA (LPT-first) U edge scatter --------------------
// Unified 16B record {off40, n1, n2, off72}: ONE scattered write per edge
// (halves line-write events vs the 8B split; scattered-write amplification
// was F2's 111MB WRITE_SIZE in r9). buildA (L2-resident Wr stream) overlaps
// the scatter's write traffic.
__global__ void k_F2(const bf16* __restrict__ Wr1, const bf16* __restrict__ Wr2,
                     const u16* __restrict__ bucket_g, const int* __restrict__ toff_g,
                     const int* __restrict__ tcnt_g, float* __restrict__ Ag,
                     const u16* __restrict__ bucket_l, const int* __restrict__ toff_l,
                     const int* __restrict__ tcnt_l, float* __restrict__ Al,
                     const int* __restrict__ src, const int* __restrict__ dst,
                     const float* __restrict__ ew, const float2* __restrict__ dis12,
                     const int* __restrict__ offs, const int* __restrict__ slot,
                     float4* __restrict__ epk){
    int bx = blockIdx.x;
    if (bx < NA){
        if (bx < NB*VG) dev_buildA(Wr1, bucket_g, toff_g, tcnt_g, Ag, SG, VG, bx);
        else dev_buildA(Wr2, bucket_l, toff_l, tcnt_l, Al, SL, VL, bx - NB*VG);
        return;
    }
    int e = (bx - NA)*256 + threadIdx.x;
    int s = src[e], d = dst[e];
    int pos = offs[d] + slot[e];
    float2 a = dis12[s], b = dis12[d];
    float4 v;
    v.x = __int_as_float(s*80);    // byte offset, stride-40 bf16
    v.y = a.x * ew[e] * b.x;       // norm layer 1
    v.z = a.y * b.y;               // norm layers 2/3
    v.w = __int_as_float(s*144);   // byte offset, stride-72 bf16
    epk[pos] = v;
}

// ---------------- fused aggregate + GEMM (uint4 rows) ----------------
// Round-2 loop body (frozen — best of lane-util/prefetch/stripe variants).
// Unified 16B epk; OFF_W selects the x/w byte-offset, N_Z the y/z norm.
// Predicated parallel tail. BN partial stats fused (64-way strided atomics).
template<int QV, int GRP, int OFF_W, int N_Z>
__device__ void dev_agg(float* sAgg /* [4][QV*8] */,
                        const bf16* __restrict__ xb, const float4* __restrict__ epk,
                        const int* __restrict__ offs, const int* __restrict__ cnt,
                        const float2* __restrict__ self12,
                        const float* __restrict__ W, const float* __restrict__ bias,
                        float* __restrict__ tout, float* __restrict__ bnpart,
                        int F, int OF, int bx){
    const int LPG = 64 / GRP;
    int wave = threadIdx.x >> 6;
    int node = bx*4 + wave;
    int lane = threadIdx.x & 63;
    int grp  = lane / LPG;
    int gl   = lane % LPG;
    bool act = gl < QV;
    const char* xc = (const char*)xb;
    float a0=0,a1=0,a2=0,a3=0,a4=0,a5=0,a6=0,a7=0;
    int b = offs[node], e = b + cnt[node];
    if (act){
        int fo = gl << 4;   // lane byte offset within row
        if (grp == 0){
            float2 sw2 = self12[node];
            float sw = N_Z ? sw2.y : sw2.x;
            uint4 u = *(const uint4*)(xc + node*(QV*16) + fo);
            a0 = sw*blo(u.x); a1 = sw*bhi(u.x); a2 = sw*blo(u.y); a3 = sw*bhi(u.y);
            a4 = sw*blo(u.z); a5 = sw*bhi(u.z); a6 = sw*blo(u.w); a7 = sw*bhi(u.w);
        }
        int p = b + grp;
        for (; p + 3*GRP < e; p += 4*GRP){
            float4 e0 = epk[p];
            float4 e1 = epk[p +   GRP];
            float4 e2 = epk[p + 2*GRP];
            float4 e3 = epk[p + 3*GRP];
            int o0 = __float_as_int(OFF_W ? e0.w : e0.x); float n0 = N_Z ? e0.z : e0.y;
            int o1 = __float_as_int(OFF_W ? e1.w : e1.x); float n1 = N_Z ? e1.z : e1.y;
            int o2 = __float_as_int(OFF_W ? e2.w : e2.x); float n2 = N_Z ? e2.z : e2.y;
            int o3 = __float_as_int(OFF_W ? e3.w : e3.x); float n3 = N_Z ? e3.z : e3.y;
            uint4 u0 = *(const uint4*)(xc + o0 + fo);
            uint4 u1 = *(const uint4*)(xc + o1 + fo);
            uint4 u2 = *(const uint4*)(xc + o2 + fo);
            uint4 u3 = *(const uint4*)(xc + o3 + fo);
            a0 += n0*blo(u0.x); a1 += n0*bhi(u0.x); a2 += n0*blo(u0.y); a3 += n0*bhi(u0.y);
            a4 += n0*blo(u0.z); a5 += n0*bhi(u0.z); a6 += n0*blo(u0.w); a7 += n0*bhi(u0.w);
            a0 += n1*blo(u1.x); a1 += n1*bhi(u1.x); a2 += n1*blo(u1.y); a3 += n1*bhi(u1.y);
            a4 += n1*blo(u1.z); a5 += n1*bhi(u1.z); a6 += n1*blo(u1.w); a7 += n1*bhi(u1.w);
            a0 += n2*blo(u2.x); a1 += n2*bhi(u2.x); a2 += n2*blo(u2.y); a3 += n2*bhi(u2.y);
            a4 += n2*blo(u2.z); a5 += n2*bhi(u2.z); a6 += n2*blo(u2.w); a7 += n2*bhi(u2.w);
            a0 += n3*blo(u3.x); a1 += n3*bhi(u3.x); a2 += n3*blo(u3.y); a3 += n3*bhi(u3.y);
            a4 += n3*blo(u3.z); a5 += n3*bhi(u3.z); a6 += n3*blo(u3.w); a7 += n3*bhi(u3.w);
        }
        if (p < e){   // predicated tail, <= 3 edges per group
            int p1 = p + GRP, p2 = p + 2*GRP;
            bool v1 = p1 < e, v2 = p2 < e;
            float4 e0 = epk[p];
            float4 e1 = epk[v1 ? p1 : p];
            float4 e2 = epk[v2 ? p2 : p];
            int o0 = __float_as_int(OFF_W ? e0.w : e0.x);
            int o1 = __float_as_int(OFF_W ? e1.w : e1.x);
            int o2 = __float_as_int(OFF_W ? e2.w : e2.x);
            float n0 = N_Z ? e0.z : e0.y;
            float n1 = v1 ? (N_Z ? e1.z : e1.y) : 0.f;
            float n2 = v2 ? (N_Z ? e2.z : e2.y) : 0.f;
            uint4 u0 = *(const uint4*)(xc + o0 + fo);
            uint4 u1 = *(const uint4*)(xc + o1 + fo);
            uint4 u2 = *(const uint4*)(xc + o2 + fo);
            a0 += n0*blo(u0.x); a1 += n0*bhi(u0.x); a2 += n0*blo(u0.y); a3 += n0*bhi(u0.y);
            a4 += n0*blo(u0.z); a5 += n0*bhi(u0.z); a6 += n0*blo(u0.w); a7 += n0*bhi(u0.w);
            a0 += n1*blo(u1.x); a1 += n1*bhi(u1.x); a2 += n1*blo(u1.y); a3 += n1*bhi(u1.y);
            a4 += n1*blo(u1.z); a5 += n1*bhi(u1.z); a6 += n1*blo(u1.w); a7 += n1*bhi(u1.w);
            a0 += n2*blo(u2.x); a1 += n2*bhi(u2.x); a2 += n2*blo(u2.y); a3 += n2*bhi(u2.y);
            a4 += n2*blo(u2.z); a5 += n2*bhi(u2.z); a6 += n2*blo(u2.w); a7 += n2*bhi(u2.w);
        }
    }
    #pragma unroll
    for (int m = LPG; m < 64; m <<= 1){
        a0 += __shfl_xor(a0, m); a1 += __shfl_xor(a1, m);
        a2 += __shfl_xor(a2, m); a3 += __shfl_xor(a3, m);
        a4 += __shfl_xor(a4, m); a5 += __shfl_xor(a5, m);
        a6 += __shfl_xor(a6, m); a7 += __shfl_xor(a7, m);
    }
    if (act && grp == 0){
        float4* dst = (float4*)&sAgg[wave*(QV*8) + gl*8];
        dst[0] = make_float4(a0, a1, a2, a3);
        dst[1] = make_float4(a4, a5, a6, a7);
    }
    __syncthreads();
    int i0 = bx*4;
    int j = threadIdx.x;
    if (j < OF){
        float c0 = bias[j], c1 = c0, c2 = c0, c3 = c0;
        const float* Wj = W + j;
        const float* s0 = sAgg;
        const float* s1 = sAgg + QV*8;
        const float* s2 = sAgg + 2*QV*8;
        const float* s3 = sAgg + 3*QV*8;
        #pragma unroll 4
        for (int f = 0; f < F; ++f){
            float w = Wj[f*OF];
            c0 += s0[f]*w; c1 += s1[f]*w; c2 += s2[f]*w; c3 += s3[f]*w;
        }
        tout[(size_t)(i0+0)*OF + j] = c0;
        tout[(size_t)(i0+1)*OF + j] = c1;
        tout[(size_t)(i0+2)*OF + j] = c2;
        tout[(size_t)(i0+3)*OF + j] = c3;
        // fused BN partial stats (64-way strided to dodge contention)
        float s  = c0 + c1 + c2 + c3;
        float ss = c0*c0 + c1*c1 + c2*c2 + c3*c3;
        float* part = bnpart + (bx & 63)*(2*OF);
        unsafeAtomicAdd(&part[j], s);
        unsafeAtomicAdd(&part[OF + j], ss);
    }
}

template<int QV, int GRP, int OFF_W, int N_Z>
__global__ __launch_bounds__(256, 8)
void k_agg_gemm(const bf16* __restrict__ xb, const float4* __restrict__ epk,
                const int* __restrict__ offs, const int* __restrict__ cnt,
                const float2* __restrict__ self12,
                const float* __restrict__ W, const float* __restrict__ bias,
                float* __restrict__ tout, float* __restrict__ bnpart,
                int F, int OF){
    __shared__ float sAgg[4*QV*8];
    dev_agg<QV,GRP,OFF_W,N_Z>(sAgg, xb, epk, offs, cnt, self12, W, bias,
                              tout, bnpart, F, OF, blockIdx.x);
}

// gemmR for 256 threads: 8 b-rows x 256-K slice, atomic epilogue
__device__ void dev_gemmR(float* xs /* [8][256] */, int bq,
                          const float* __restrict__ Ag, const bf16* __restrict__ G1,
                          const float* __restrict__ Al, const bf16* __restrict__ G2,
                          float* __restrict__ out0){
    int kpart = bq >> 4;       // 0..69
    int bgrp  = bq & 15;
    const float* X; const bf16* G; int K, k0;
    if (kpart < 5){ X = Ag; G = G1; K = 1280;  k0 = kpart*256; }
    else          { X = Al; G = G2; K = 16640; k0 = (kpart-5)*256; }
    int b0 = bgrp*8;
    int t = threadIdx.x;
    #pragma unroll
    for (int i = 0; i < 8; ++i)
        xs[i*256 + t] = X[(b0+i)*K + k0 + t];
    __syncthreads();
    int rq = t >> 7, j = t & 127;
    const float* x0 = xs + (rq*4)*256;
    float a0=0,a1=0,a2=0,a3=0;
    const bf16* Gp = G + (size_t)k0*128 + j;
    for (int kk = 0; kk < 256; ++kk){
        float g = b2f(Gp[kk*128]);
        a0 += x0[kk]*g; a1 += x0[256+kk]*g; a2 += x0[512+kk]*g; a3 += x0[768+kk]*g;
    }
    unsafeAtomicAdd(&out0[(b0+rq*4+0)*128 + j], 0.5f*a0);
    unsafeAtomicAdd(&out0[(b0+rq*4+1)*128 + j], 0.5f*a1);
    unsafeAtomicAdd(&out0[(b0+rq*4+2)*128 + j], 0.5f*a2);
    unsafeAtomicAdd(&out0[(b0+rq*4+3)*128 + j], 0.5f*a3);
}

// L3 aggregate+gemm  U  gemmR (RNA head backfills L3's latency stalls)
__global__ void k_L3(const bf16* __restrict__ xb, const float4* __restrict__ epk,
                     const int* __restrict__ offs, const int* __restrict__ cnt,
                     const float2* __restrict__ self12,
                     const float* __restrict__ W, const float* __restrict__ bias,
                     float* __restrict__ tout, float* __restrict__ bnpart,
                     const float* __restrict__ Ag, const bf16* __restrict__ G1,
                     const float* __restrict__ Al, const bf16* __restrict__ G2,
                     float* __restrict__ out0){
    __shared__ float smem[8*256];
    int bx = blockIdx.x;
    if (bx < AGB){
        dev_agg<9,4,1,1>(smem, xb, epk, offs, cnt, self12, W, bias, tout, bnpart,
                         66, 132, bx);
    } else {
        dev_gemmR(smem, bx - AGB, Ag, G1, Al, G2, out0);
    }
}

// reduce 64-way strided BN partials -> sums (1 block)
__global__ void k_bn_fin(const float* __restrict__ part, float* __restrict__ sums, int OF){
    int tid = threadIdx.x;
    if (tid >= 2*OF) return;
    float s = 0.f;
    #pragma unroll 8
    for (int k = 0; k < 64; ++k) s += part[k*(2*OF) + tid];
    sums[tid] = s;
}

// fused finalize+apply, flattened; padded bf16 out (stride OS)
__global__ void k_bn_apply(const float* __restrict__ t, const float* __restrict__ sums,
                           const float* __restrict__ g, const float* __restrict__ b,
                           bf16* __restrict__ xo, int OF, int OS, int total){
    int id = blockIdx.x*256 + threadIdx.x;
    if (id >= total) return;
    int i = id / OS, f = id - i*OS;
    float v = 0.f;
    if (f < OF){
        float m  = sums[f] * (1.0f/(float)NN);
        float vr = sums[OF + f] * (1.0f/(float)NN) - m*m;
        float sc = g[f] * rsqrtf(vr + 1e-5f);
        float sh = b[f] - m*sc;
        v = t[(size_t)i*OF + f] * sc + sh;
        v = v > 0.f ? v : 0.f;
    }
    xo[id] = __float2bfloat16(v);
}

// fused BN3-apply + pool + fcg1 + fcg2: block g does everything for graph g
// (reads finalized bnsum3 -> no extra atomic contention)
__global__ void k_fcgF(const float* __restrict__ bufB, const float* __restrict__ sums,
                       const float* __restrict__ bn3g, const float* __restrict__ bn3b,
                       const int* __restrict__ gstart,
                       const float* __restrict__ W1, const float* __restrict__ b1,
                       const float* __restrict__ W2, const float* __restrict__ b2,
                       float* __restrict__ out){
    __shared__ float scs[132], shs[132];
    __shared__ float pp[7][132];
    __shared__ float pr[132];
    __shared__ float hr[1024];
    __shared__ float part[8][128];
    int g = blockIdx.x, t = threadIdx.x;   // 1024
    if (t < 132){
        float m  = sums[t] * (1.0f/(float)NN);
        float vr = sums[132 + t] * (1.0f/(float)NN) - m*m;
        float sc = bn3g[t] * rsqrtf(vr + 1e-5f);
        scs[t] = sc;
        shs[t] = bn3b[t] - m*sc;
    }
    __syncthreads();
    int i0 = gstart[g], i1 = gstart[g+1];
    int r = t / 132, f = t - r*132;
    if (r < 7){
        float acc = 0.f;
        for (int i = i0 + r; i < i1; i += 7){
            float v = bufB[(size_t)i*132 + f] * scs[f] + shs[f];
            acc += v > 0.f ? v : 0.f;
        }
        pp[r][f] = acc;
    }
    __syncthreads();
    if (t < 132){
        float s = 0.f;
        #pragma unroll
        for (int k = 0; k < 7; ++k) s += pp[k][t];
        float inv = 1.0f / fmaxf((float)(i1 - i0), 1.0f);
        pr[t] = s * inv;
    }
    __syncthreads();
    float acc = b1[t];
    #pragma unroll 4
    for (int ff = 0; ff < 132; ++ff) acc += pr[ff] * W1[ff*1024 + t];
    hr[t] = acc > 0.f ? acc : 0.f;
    __syncthreads();
    int ks = t >> 7, j = t & 127;
    const float* Wp = W2 + (ks*128)*128 + j;
    const float* hp = hr + ks*128;
    float a = 0.f;
    #pragma unroll 8
    for (int kk = 0; kk < 128; ++kk) a += hp[kk] * Wp[(size_t)kk*128];
    part[ks][j] = a;
    __syncthreads();
    if (t < 128){
        float s = b2[t];
        #pragma unroll
        for (int rr = 0; rr < 8; ++rr) s += part[rr][t];
        out[g*128 + t] = s;
    }
}

extern "C" void kernel_launch(void* const* d_in, const int* in_sizes, int n_in,
                              void* d_out, int out_size, void* d_ws, size_t ws_size,
                              hipStream_t stream)
{
    (void)in_sizes; (void)n_in; (void)out_size; (void)ws_size;

    const float* pro_x  = (const float*)d_in[0];
    const int*   eidx   = (const int*)  d_in[1];
    const float* ew     = (const float*)d_in[2];
    const int*   pbatch = (const int*)  d_in[3];
    const int*   rna_g  = (const int*)  d_in[4];
    const int*   rna_l  = (const int*)  d_in[5];
    const float* emb1   = (const float*)d_in[6];
    const float* emb2   = (const float*)d_in[7];
    const float* convW1 = (const float*)d_in[8];
    const float* convb1 = (const float*)d_in[9];
    const float* convW2 = (const float*)d_in[10];
    const float* convb2 = (const float*)d_in[11];
    const float* fcxrW  = (const float*)d_in[12];
    const float* fcxrb  = (const float*)d_in[13];
    const float* g1W = (const float*)d_in[14];
    const float* g1b = (const float*)d_in[15];
    const float* g2W = (const float*)d_in[16];
    const float* g2b = (const float*)d_in[17];
    const float* g3W = (const float*)d_in[18];
    const float* g3b = (const float*)d_in[19];
    const float* bn1g = (const float*)d_in[20];
    const float* bn1b = (const float*)d_in[21];
    const float* bn2g = (const float*)d_in[22];
    const float* bn2b = (const float*)d_in[23];
    const float* bn3g = (const float*)d_in[24];
    const float* bn3b = (const float*)d_in[25];
    const float* fcg1W = (const float*)d_in[26];
    const float* fcg1b = (const float*)d_in[27];
    const float* fcg2W = (const float*)d_in[28];
    const float* fcg2b = (const float*)d_in[29];

    const int* e_src = eidx;
    const int* e_dst = eidx + NE;

    char* base = (char*)d_ws;
    size_t off = 0;
    auto alloc = [&](size_t bytes)->char*{
        off = (off + 255) & ~(size_t)255;
        char* p = base + off; off += bytes; return p;
    };

    // ---- zero zone (single memset) ----
    double* packed  = (double*)alloc(NN*8);
    float* bnsum1  = (float*)alloc(2*33*4);
    float* bnsum2  = (float*)alloc(2*66*4);
    float* bnsum3  = (float*)alloc(2*132*4);
    float* bias0   = (float*)alloc(128*4);
    float* bnpart1 = (float*)alloc(64*2*33*4);
    float* bnpart2 = (float*)alloc(64*2*66*4);
    float* bnpart3 = (float*)alloc(64*2*132*4);
    size_t zero_bytes = (off + 255) & ~(size_t)255;

    // ---- persistent buffers ----
    int*    cnt    = (int*)   alloc(NN*4);
    float2* dis12  = (float2*)alloc(NN*8);
    float2* self12 = (float2*)alloc(NN*8);
    int*    offs   = (int*)   alloc(NN*4);
    int*    bsum   = (int*)   alloc(64*4);
    int*    gstart = (int*)   alloc((NG+1)*4);
    float4* epk    = (float4*)alloc((size_t)NE*16);
    float*  bufB   = (float*) alloc((size_t)NN*132*4);   // t (max OF=132)
    bf16*   xbA    = (bf16*)  alloc((size_t)NE*4);       // >= max(slot 6.4MB, NN*40*2)
    bf16*   xbB    = (bf16*)  alloc((size_t)NN*72*2);    // stride-72 features
    float*  Ag     = (float*) alloc((size_t)NB*256*VG*4);   // persistent: read by k_L3
    float*  Al     = (float*) alloc((size_t)NB*256*VL*4);
    bf16*   G1     = (bf16*)  alloc((size_t)32*8*VG*128*2);
    bf16*   G2     = (bf16*)  alloc((size_t)32*8*VL*128*2);

    // slot aliases xbA (consumed by F2 scatter before L1 bn_apply writes xbA)
    int*  slot = (int*)xbA;
    // xb0 (stride-40 cast, 4MB) aliases xbB: front cast -> agg1 reads xb0 ->
    // bn_apply2 overwrites xbB. Safe.
    bf16* xb0  = (bf16*)xbB;

    float* out0 = (float*)d_out;          // xc_rna
    float* out1 = (float*)d_out + 16384;  // xp_out

    // ---- RNA scratch aliased onto bufB (written by k_front, consumed by
    // k_F2 buildA; both complete before agg1 writes bufB) ----
    char* rb = (char*)bufB;
    size_t ro = 0;
    auto ralloc = [&](size_t bytes)->char*{
        ro = (ro + 255) & ~(size_t)255;
        char* p = rb + ro; ro += bytes; return p;
    };
    int* toff_g   = (int*)ralloc(NB*VG*4);
    int* toff_l   = (int*)ralloc(NB*VL*4);
    int* tcnt_g   = (int*)ralloc(NB*VG*4);
    int* tcnt_l   = (int*)ralloc(NB*VL*4);
    u16* bucket_g = (u16*)ralloc((size_t)NB*SG*2);
    u16* bucket_l = (u16*)ralloc((size_t)NB*SL*2);
    bf16* Wr1     = (bf16*)ralloc((size_t)SG*256*2);
    bf16* Wr2     = (bf16*)ralloc((size_t)SL*256*2);

    hipMemsetAsync(d_ws, 0, zero_bytes, stream);

    // ---- front: bucketing U buildG U edge_deg U transposeW U cast U bias0 --
    k_front<<<2*NB + NGB + EDB + SG + SL + CASTB + 32, 256, 0, stream>>>(
        rna_g, rna_l, tcnt_g, toff_g, bucket_g, tcnt_l, toff_l, bucket_l,
        convW1, convW2, Wr1, Wr2, fcxrW, convb1, convb2, bias0,
        e_dst, ew, packed, slot,
        emb1, emb2, G1, G2, pro_x, xb0);

    // ---- prep (50 blocks) + scan ----
    k_prep<<<50, 256, 0, stream>>>(packed, cnt, dis12, self12, pbatch, gstart,
                                   bsum, fcxrb, bias0, out0);
    k_scan3<<<49, 256, 0, stream>>>(cnt, bsum, offs);

    // ---- F2: buildA (LPT-first, L2-resident Wr) U edge scatter (16B) ----
    k_F2<<<NA + EDB, 256, 0, stream>>>(Wr1, Wr2,
                                       bucket_g, toff_g, tcnt_g, Ag,
                                       bucket_l, toff_l, tcnt_l, Al,
                                       e_src, e_dst, ew, dis12, offs, slot, epk);

    // ---- GCN layer 1 (33 -> 33), input stride 40 ----
    k_agg_gemm<5,8,0,0><<<AGB, 256, 0, stream>>>(xb0, epk, offs, cnt, self12,
                                                 g1W, g1b, bufB, bnpart1, 33, 33);
    k_bn_fin<<<1, 512, 0, stream>>>(bnpart1, bnsum1, 33);
    k_bn_apply<<<(NN*40+255)/256, 256, 0, stream>>>(bufB, bnsum1, bn1g, bn1b,
                                                    xbA, 33, 40, NN*40);

    // ---- GCN layer 2 (33 -> 66), input stride 40 (xbA), output stride 72 ----
    k_agg_gemm<5,8,0,1><<<AGB, 256, 0, stream>>>(xbA, epk, offs, cnt, self12,
                                                 g2W, g2b, bufB, bnpart2, 33, 66);
    k_bn_fin<<<1, 512, 0, stream>>>(bnpart2, bnsum2, 66);
    k_bn_apply<<<(NN*72+255)/256, 256, 0, stream>>>(bufB, bnsum2, bn2g, bn2b,
                                                    xbB, 66, 72, NN*72);

    // ---- GCN layer 3 (66 -> 132)  U  RNA-head gemmR ----
    k_L3<<<AGB + 1120, 256, 0, stream>>>(xbB, epk, offs, cnt, self12,
                                         g3W, g3b, bufB, bnpart3, Ag, G1, Al, G2, out0);
    k_bn_fin<<<1, 512, 0, stream>>>(bnpart3, bnsum3, 132);

    // ---- fused BN3-apply + pool + fcg1 + fcg2 ----
    k_fcgF<<<NG, 1024, 0, stream>>>(bufB, bnsum3, bn3g, bn3b, gstart,
                                    fcg1W, fcg1b, fcg2W, fcg2b, out1);
}